// Round 6
// baseline (799.268 us; speedup 1.0000x reference)
//
#include <hip/hip_runtime.h>

// ---------------------------------------------------------------------------
// SPDBatchNormMean forward, B=8192, n=64, fp32. Eigendecomp-free:
//   G0 = mean(x); Gs/Gis = G0^{±1/2} (Newton-Schulz); M = mean log(Gis x Gis)
//   (deg-18 Chebyshev on [0.3,4.0]); G1 = Gs expm(M) Gs; Gis1 = G1^{-1/2};
//   C = Bs Gis1 (Bs = bias^{1/2}); out = C x C^T.
// Round 8: force the VGPR budget with amdgpu_waves_per_eu(4,4).
// Round-7 showed __launch_bounds__(1024,4) is only a MINIMUM waves/EU (caps
// VGPRs at 128 but doesn't stop the allocator choosing 64 for an 8-wave/EU
// occupancy the 116KB LDS makes impossible). Counters were byte-identical to
// round 6: VGPR 64, ~300MB of spill traffic. waves_per_eu(4,4) clamps BOTH
// bounds: max 4 waves/EU -> shrinking below 512/4=128 VGPRs gains nothing ->
// allocator expands to fit the ~122 live regs (Mac+tm1/tm2+acc+uh/ul).
// Everything else identical to round 7 (single-variable A/B).
// ---------------------------------------------------------------------------

#define BATCH 8192
#define NMAT 64
#define MSIZE 4096
#define NBLK_RED 512
#define NBLK_K3 256
#define K3_CHAINS 4
#define CHAIN_MATS 8
#define NBLK_K5 256
#define DEG 18
#define CHEB_LO 0.30f
#define CHEB_HI 4.00f
#define NS_ITERS_MEAN 10
#define NS_ITERS_BIAS 12
#define GSTR 520 /* padded k-group stride (65*8 elems, 16B-aligned) */

// workspace layout (floats): only the 6 small matrices (96 KB).
#define G_OFF 0
#define BS_OFF (G_OFF + MSIZE)
#define GS_OFF (BS_OFF + MSIZE)
#define GIS_OFF (GS_OFF + MSIZE)
#define MBAR_OFF (GIS_OFF + MSIZE)
#define C_OFF (MBAR_OFF + MSIZE)
// scratch staged in `out` (128 MB, dead until k5): partial slots [0,1024),
// stage-1 reduce slots at [RED1_SLOT, RED1_SLOT+64).
#define RED1_SLOT 2048

typedef __attribute__((ext_vector_type(8))) short bf16x8;
typedef __attribute__((ext_vector_type(16))) float floatx16;
#define MFMA(a, b, c) __builtin_amdgcn_mfma_f32_32x32x16_bf16(a, b, c, 0, 0, 0)

__device__ __forceinline__ short f2bf(float x) {
  union {
    __bf16 b;
    short s;
  } u;
  u.b = (__bf16)x;  // hardware cvt, RNE
  return u.s;
}
__device__ __forceinline__ float bf2f(short h) {
  return __uint_as_float(((unsigned)(unsigned short)h) << 16);
}

// Stage a row-major 64x64 fp32 global matrix M into hi/lo bf16 LDS arrays in
// B-layout holding M^T: arr(k,n) = M[n][k]. 256 threads (st), packed b64.
__device__ __forceinline__ void stageT(const float* __restrict__ src, short* ah,
                                       short* al, int st) {
#pragma unroll
  for (int jb = 0; jb < 4; ++jb) {
    int flat = jb * 1024 + st * 4;
    float4 v = *reinterpret_cast<const float4*>(src + flat);
    int i = flat >> 6;   // row of M
    int j0 = flat & 63;  // col base (multiple of 4)
    int addr = (j0 >> 3) * GSTR + i * 8 + (j0 & 7);
    short4 h, l;
    h.x = f2bf(v.x); l.x = f2bf(v.x - bf2f(h.x));
    h.y = f2bf(v.y); l.y = f2bf(v.y - bf2f(h.y));
    h.z = f2bf(v.z); l.z = f2bf(v.z - bf2f(h.z));
    h.w = f2bf(v.w); l.w = f2bf(v.w - bf2f(h.w));
    *reinterpret_cast<short4*>(ah + addr) = h;
    *reinterpret_cast<short4*>(al + addr) = l;
  }
}

// Fragment read: returns elements j=0..7 at k = kb*16 + q*8 + j, column n.
__device__ __forceinline__ bf16x8 readFrag(const short* a, int kb, int q,
                                           int n) {
  return *reinterpret_cast<const bf16x8*>(a + (kb * 2 + q) * GSTR + n * 8);
}

// Store 16 C/D-layout fp32 regs into B-layout array(s) as bf16 (direct:
// arr(k=row, n=col) = v). Packs 4 consecutive rows per b64 write.
__device__ __forceinline__ void storeChi(short* dh, const float* v, int R,
                                         int col, int q) {
#pragma unroll
  for (int g4 = 0; g4 < 4; ++g4) {
    int addr = (4 * R + g4) * GSTR + col * 8 + 4 * q;
    short4 h;
    h.x = f2bf(v[4 * g4 + 0]);
    h.y = f2bf(v[4 * g4 + 1]);
    h.z = f2bf(v[4 * g4 + 2]);
    h.w = f2bf(v[4 * g4 + 3]);
    *reinterpret_cast<short4*>(dh + addr) = h;
  }
}
__device__ __forceinline__ void storeChl(short* dh, short* dl, const float* v,
                                         int R, int col, int q) {
#pragma unroll
  for (int g4 = 0; g4 < 4; ++g4) {
    int addr = (4 * R + g4) * GSTR + col * 8 + 4 * q;
    short4 h, l;
    float a0 = v[4 * g4 + 0], a1 = v[4 * g4 + 1];
    float a2 = v[4 * g4 + 2], a3 = v[4 * g4 + 3];
    h.x = f2bf(a0); l.x = f2bf(a0 - bf2f(h.x));
    h.y = f2bf(a1); l.y = f2bf(a1 - bf2f(h.y));
    h.z = f2bf(a2); l.z = f2bf(a2 - bf2f(h.z));
    h.w = f2bf(a3); l.w = f2bf(a3 - bf2f(h.w));
    *reinterpret_cast<short4*>(dh + addr) = h;
    *reinterpret_cast<short4*>(dl + addr) = l;
  }
}

// ============================ vector-ALU helpers (k1/k2/k4) ================

__device__ __forceinline__ void mm64T(const float* __restrict__ A,
                                      const float* __restrict__ B, int rt,
                                      int ct, float p[4][4]) {
#pragma unroll
  for (int i = 0; i < 4; ++i)
#pragma unroll
    for (int j = 0; j < 4; ++j) p[i][j] = 0.0f;
#pragma unroll 4
  for (int k = 0; k < NMAT; ++k) {
    float4 a = *reinterpret_cast<const float4*>(A + k * NMAT + rt * 4);
    float4 b = *reinterpret_cast<const float4*>(B + k * NMAT + ct * 4);
    p[0][0] = fmaf(a.x, b.x, p[0][0]);
    p[0][1] = fmaf(a.x, b.y, p[0][1]);
    p[0][2] = fmaf(a.x, b.z, p[0][2]);
    p[0][3] = fmaf(a.x, b.w, p[0][3]);
    p[1][0] = fmaf(a.y, b.x, p[1][0]);
    p[1][1] = fmaf(a.y, b.y, p[1][1]);
    p[1][2] = fmaf(a.y, b.z, p[1][2]);
    p[1][3] = fmaf(a.y, b.w, p[1][3]);
    p[2][0] = fmaf(a.z, b.x, p[2][0]);
    p[2][1] = fmaf(a.z, b.y, p[2][1]);
    p[2][2] = fmaf(a.z, b.z, p[2][2]);
    p[2][3] = fmaf(a.z, b.w, p[2][3]);
    p[3][0] = fmaf(a.w, b.x, p[3][0]);
    p[3][1] = fmaf(a.w, b.y, p[3][1]);
    p[3][2] = fmaf(a.w, b.z, p[3][2]);
    p[3][3] = fmaf(a.w, b.w, p[3][3]);
  }
}

__device__ __forceinline__ void storeTile(float* dst, int rt, int ct,
                                          const float p[4][4]) {
#pragma unroll
  for (int i = 0; i < 4; ++i)
    *reinterpret_cast<float4*>(dst + (rt * 4 + i) * NMAT + ct * 4) =
        make_float4(p[i][0], p[i][1], p[i][2], p[i][3]);
}

__device__ __forceinline__ void loadMat(float* dst,
                                        const float* __restrict__ src,
                                        int tid) {
#pragma unroll
  for (int j = 0; j < 4; ++j)
    *reinterpret_cast<float4*>(dst + j * 1024 + tid * 4) =
        *reinterpret_cast<const float4*>(src + j * 1024 + tid * 4);
}

__device__ __forceinline__ float4 id4(int base) {
  return make_float4(((base + 0) % 65) == 0 ? 1.f : 0.f,
                     ((base + 1) % 65) == 0 ? 1.f : 0.f,
                     ((base + 2) % 65) == 0 ? 1.f : 0.f,
                     ((base + 3) % 65) == 0 ? 1.f : 0.f);
}

__device__ float block_ns(const float* lA, float* lY, float* lZ, float* lW,
                          float* red, int iters) {
  const int tid = threadIdx.x;
  const int rt = tid >> 4, ct = tid & 15;
  float ss = 0.0f;
#pragma unroll
  for (int j = 0; j < 4; ++j) {
    float4 v = *reinterpret_cast<const float4*>(lA + j * 1024 + tid * 4);
    ss += v.x * v.x + v.y * v.y + v.z * v.z + v.w * v.w;
  }
  red[tid] = ss;
  __syncthreads();
  for (int off = 128; off > 0; off >>= 1) {
    if (tid < off) red[tid] += red[tid + off];
    __syncthreads();
  }
  const float c = sqrtf(red[0] * 0.5f);
  const float rc = 1.0f / c;
#pragma unroll
  for (int j = 0; j < 4; ++j) {
    int base = j * 1024 + tid * 4;
    float4 v = *reinterpret_cast<const float4*>(lA + base);
    v.x *= rc;
    v.y *= rc;
    v.z *= rc;
    v.w *= rc;
    *reinterpret_cast<float4*>(lY + base) = v;
    *reinterpret_cast<float4*>(lZ + base) = id4(base);
  }
  __syncthreads();
  for (int it = 0; it < iters; ++it) {
    float p[4][4];
    mm64T(lZ, lY, rt, ct, p);
    float w[4][4];
#pragma unroll
    for (int i = 0; i < 4; ++i)
#pragma unroll
      for (int j = 0; j < 4; ++j)
        w[i][j] = ((rt * 4 + i) == (ct * 4 + j) ? 1.5f : 0.0f) - 0.5f * p[i][j];
    storeTile(lW, rt, ct, w);
    __syncthreads();
    float py[4][4], pz[4][4];
    mm64T(lY, lW, rt, ct, py);
    mm64T(lW, lZ, rt, ct, pz);
    __syncthreads();
    storeTile(lY, rt, ct, py);
    storeTile(lZ, rt, ct, pz);
    __syncthreads();
  }
  return c;
}

// K1: blocks [0,NBLK_RED) partial-sum x into `pg` (out scratch); block
// NBLK_RED does Bs = bias^{1/2}.
__global__ __launch_bounds__(256) void k1_mean_bias(
    const float* __restrict__ x, const float* __restrict__ bias,
    float* __restrict__ ws, float* __restrict__ pg) {
  const int tid = threadIdx.x;
  if (blockIdx.x < NBLK_RED) {
    float acc[16];
#pragma unroll
    for (int j = 0; j < 16; ++j) acc[j] = 0.f;
    for (int i = blockIdx.x; i < BATCH; i += NBLK_RED) {
      const float* src = x + (size_t)i * MSIZE;
#pragma unroll
      for (int j = 0; j < 4; ++j) {
        float4 v = *reinterpret_cast<const float4*>(src + j * 1024 + tid * 4);
        acc[j * 4 + 0] += v.x;
        acc[j * 4 + 1] += v.y;
        acc[j * 4 + 2] += v.z;
        acc[j * 4 + 3] += v.w;
      }
    }
    float* dst = pg + (size_t)blockIdx.x * MSIZE;
#pragma unroll
    for (int j = 0; j < 4; ++j)
      *reinterpret_cast<float4*>(dst + j * 1024 + tid * 4) = make_float4(
          acc[j * 4 + 0], acc[j * 4 + 1], acc[j * 4 + 2], acc[j * 4 + 3]);
  } else {
    __shared__ __align__(16) float lA[MSIZE], lY[MSIZE], lZ[MSIZE], lW[MSIZE];
    __shared__ float red[257];
    loadMat(lA, bias, tid);
    __syncthreads();
    float c = block_ns(lA, lY, lZ, lW, red, NS_ITERS_BIAS);
    float sc = sqrtf(c);
#pragma unroll
    for (int j = 0; j < 4; ++j) {
      int base = j * 1024 + tid * 4;
      float4 v = *reinterpret_cast<const float4*>(lY + base);
      v.x *= sc;
      v.y *= sc;
      v.z *= sc;
      v.w *= sc;
      *reinterpret_cast<float4*>(ws + BS_OFF + base) = v;
    }
  }
}

// Two-stage partial reduce. grid = (4, NY): block (bx, by) sums parts
// p = by, by+NY, ... for its 1 KB element range; writes slot `by` of dst.
__global__ __launch_bounds__(256) void k_reduce_parts(
    const float* __restrict__ src, float* __restrict__ dst, int nparts,
    float scale) {
  int e4 = blockIdx.x * 256 + threadIdx.x;
  float4 acc = make_float4(0.f, 0.f, 0.f, 0.f);
  for (int b = blockIdx.y; b < nparts; b += gridDim.y) {
    float4 v =
        *reinterpret_cast<const float4*>(src + (size_t)b * MSIZE + e4 * 4);
    acc.x += v.x;
    acc.y += v.y;
    acc.z += v.z;
    acc.w += v.w;
  }
  acc.x *= scale;
  acc.y *= scale;
  acc.z *= scale;
  acc.w *= scale;
  *reinterpret_cast<float4*>(dst + (size_t)blockIdx.y * MSIZE + e4 * 4) = acc;
}

__global__ __launch_bounds__(256) void k2_mean_ns(float* __restrict__ ws) {
  __shared__ __align__(16) float lA[MSIZE], lY[MSIZE], lZ[MSIZE], lW[MSIZE];
  __shared__ float red[257];
  const int tid = threadIdx.x;
  loadMat(lA, ws + G_OFF, tid);
  __syncthreads();
  float c = block_ns(lA, lY, lZ, lW, red, NS_ITERS_MEAN);
  float sc = sqrtf(c), rs = 1.0f / sqrtf(c);
#pragma unroll
  for (int j = 0; j < 4; ++j) {
    int base = j * 1024 + tid * 4;
    float4 y = *reinterpret_cast<const float4*>(lY + base);
    float4 z = *reinterpret_cast<const float4*>(lZ + base);
    *reinterpret_cast<float4*>(ws + GS_OFF + base) =
        make_float4(y.x * sc, y.y * sc, y.z * sc, y.w * sc);
    *reinterpret_cast<float4*>(ws + GIS_OFF + base) =
        make_float4(z.x * rs, z.y * rs, z.z * rs, z.w * rs);
  }
}

// ============================ K3: MFMA Chebyshev log-sum ====================
// 1024 threads = 4 independent 4-wave chains; grid 256 (1 block/CU, 16 waves).
// amdgpu_waves_per_eu(4,4): clamp occupancy at exactly 4 waves/EU (the LDS
// already limits us to one 16-wave block/CU) -> VGPR budget 512/4 = 128,
// fitting the ~122 live regs that were spilling at the heuristic's 64.
// 3 LDS arrays per chain (A0,A1,A2): X/P0/U time-share (A0,A1) with extra
// barriers; recurrence ping-pongs A2 <-> A0 (U cached in registers).
__global__ __launch_bounds__(1024)
__attribute__((amdgpu_waves_per_eu(4, 4))) void k3_logsum_mfma(
    const float* __restrict__ x, const float* __restrict__ ws,
    float* __restrict__ pm) {
  __shared__ __align__(16) short GisH[GSTR * 8], GisL[GSTR * 8];
  __shared__ __align__(16) short SH[K3_CHAINS][3][GSTR * 8];
  const int tid = threadIdx.x;
  const int ch = tid >> 8;   // chain 0..3
  const int ct = tid & 255;  // thread within chain
  const int w4 = ct >> 6;    // wave within chain
  const int R = w4 >> 1, Cb = w4 & 1;
  const int lane = tid & 63;
  const int ln = lane & 31, q = lane >> 5;
  const int col = 32 * Cb + ln;
  short* A0 = SH[ch][0];
  short* A1 = SH[ch][1];
  short* A2 = SH[ch][2];

  const float m = 0.5f * (CHEB_LO + CHEB_HI), hh = 0.5f * (CHEB_HI - CHEB_LO);
  const float invh = 1.0f / hh;
  const float beta = hh / m;
  const float zeta = (1.0f - sqrtf(1.0f - beta * beta)) / beta;
  const float ca0 = logf(m) - log1pf(zeta * zeta);
  const float ca1 = 2.0f * zeta;

  // diagonal index: r_dg = r for which row(r)==col (or -1). row(r) =
  // 32R + (r&3) + 8(r>>2) + 4q.
  int d = col - 32 * R - 4 * q;
  const int r_dg =
      (d >= 0 && d < 32 && (d & 4) == 0) ? ((d >> 3) * 4 + (d & 3)) : -1;

  if (ch == 0) stageT(ws + GIS_OFF, GisH, GisL, ct);
  __syncthreads();

  float Mac[16];
#pragma unroll
  for (int r = 0; r < 16; ++r) Mac[r] = 0.0f;

  for (int it = 0; it < CHAIN_MATS; ++it) {
    const int mat = blockIdx.x * (K3_CHAINS * CHAIN_MATS) + ch * CHAIN_MATS + it;
    stageT(x + (size_t)mat * MSIZE, A0, A1, ct);
    __syncthreads();
    // mm1: P0 = X * Gis   (A = X frags from A0/A1, B = Gis shared)
    floatx16 acc;
#pragma unroll
    for (int r = 0; r < 16; ++r) acc[r] = 0.0f;
#pragma unroll
    for (int kb = 0; kb < 4; ++kb) {
      bf16x8 axh = readFrag(A0, kb, q, 32 * R + ln);
      bf16x8 axl = readFrag(A1, kb, q, 32 * R + ln);
      bf16x8 gbh = readFrag(GisH, kb, q, col);
      bf16x8 gbl = readFrag(GisL, kb, q, col);
      acc = MFMA(axl, gbh, acc);
      acc = MFMA(axh, gbl, acc);
      acc = MFMA(axh, gbh, acc);
    }
    __syncthreads();  // all waves finished reading X from A0/A1
    float tmp[16];
#pragma unroll
    for (int r = 0; r < 16; ++r) tmp[r] = acc[r];
    storeChl(A0, A1, tmp, R, col, q);  // P0 overwrites X
    __syncthreads();
    // mm2: S = Gis * P0 -> U = (S - mI)/h
#pragma unroll
    for (int r = 0; r < 16; ++r) acc[r] = 0.0f;
#pragma unroll
    for (int kb = 0; kb < 4; ++kb) {
      bf16x8 gah = readFrag(GisH, kb, q, 32 * R + ln);
      bf16x8 gal = readFrag(GisL, kb, q, 32 * R + ln);
      bf16x8 bph = readFrag(A0, kb, q, col);
      bf16x8 bpl = readFrag(A1, kb, q, col);
      acc = MFMA(gal, bph, acc);
      acc = MFMA(gah, bpl, acc);
      acc = MFMA(gah, bph, acc);
    }
    float u[16], tm1[16], tm2[16];
#pragma unroll
    for (int r = 0; r < 16; ++r) {
      float dgr = (r == r_dg) ? 1.0f : 0.0f;
      u[r] = (acc[r] - m * dgr) * invh;
      Mac[r] += ca0 * dgr + ca1 * u[r];
      tm1[r] = u[r];
      tm2[r] = dgr;  // T0 = I
    }
    __syncthreads();  // all waves finished reading P0 from A0/A1
    storeChl(A0, A1, u, R, col, q);  // U overwrites P0
    __syncthreads();
    bf16x8 uh[4], ul[4];
#pragma unroll
    for (int kb = 0; kb < 4; ++kb) {  // A-op U via symmetry -> registers
      uh[kb] = readFrag(A0, kb, q, 32 * R + ln);
      ul[kb] = readFrag(A1, kb, q, 32 * R + ln);
    }
    // k = 2: T2 = 2 U*U - I (B-op U from A0/A1, hi/lo)
#pragma unroll
    for (int r = 0; r < 16; ++r) acc[r] = 0.0f;
#pragma unroll
    for (int kb = 0; kb < 4; ++kb) {
      bf16x8 buh = readFrag(A0, kb, q, col);
      bf16x8 bul = readFrag(A1, kb, q, col);
      acc = MFMA(ul[kb], buh, acc);
      acc = MFMA(uh[kb], bul, acc);
      acc = MFMA(uh[kb], buh, acc);
    }
    float zk = zeta * zeta;
    float ak = -zk;  // -2*zk/2
    float t[16];
#pragma unroll
    for (int r = 0; r < 16; ++r) {
      t[r] = 2.0f * acc[r] - tm2[r];  // tm2 == T0 here
      Mac[r] += ak * t[r];
      tm2[r] = tm1[r];
      tm1[r] = t[r];
    }
    storeChi(A2, t, R, col, q);  // T2 -> A2 (A2 idle; no WAR with A0/A1 reads)
    __syncthreads();
    // k = 3..DEG: T_k = 2 U T_{k-1} - T_{k-2}; B-op bf16-only; ping-pong
    // A2 (even T) <-> A0 (odd T). U stays in registers; A0's U copy is dead.
    for (int k = 3; k <= DEG; ++k) {
      short* src = (k & 1) ? A2 : A0;
      short* dst = (k & 1) ? A0 : A2;
#pragma unroll
      for (int r = 0; r < 16; ++r) acc[r] = 0.0f;
#pragma unroll
      for (int kb = 0; kb < 4; ++kb) {
        bf16x8 b = readFrag(src, kb, q, col);
        acc = MFMA(ul[kb], b, acc);
        acc = MFMA(uh[kb], b, acc);
      }
      zk *= -zeta;
      ak = -2.0f * zk / (float)k;
#pragma unroll
      for (int r = 0; r < 16; ++r) {
        t[r] = 2.0f * acc[r] - tm2[r];
        Mac[r] += ak * t[r];
        tm2[r] = tm1[r];
        tm1[r] = t[r];
      }
      if (k < DEG) storeChi(dst, t, R, col, q);
      __syncthreads();
    }
  }
  // per-chain partial (1024 total)
  float* dst = pm + (size_t)(blockIdx.x * K3_CHAINS + ch) * MSIZE;
#pragma unroll
  for (int r = 0; r < 16; ++r) {
    int row = 32 * R + (r & 3) + 8 * (r >> 2) + 4 * q;
    dst[row * 64 + col] = Mac[r];
  }
}

// K4: E = expm(Mbar); G1 = Gs E Gs; Gis1 = sym(G1)^{-1/2}; C = Bs Gis1 -> ws.
__global__ __launch_bounds__(256) void k4_center(float* __restrict__ ws) {
  __shared__ __align__(16) float lA[MSIZE], lY[MSIZE], lZ[MSIZE], lW[MSIZE];
  __shared__ float red[257];
  const int tid = threadIdx.x;
  const int rt = tid >> 4, ct = tid & 15;
  loadMat(lA, ws + MBAR_OFF, tid);
  __syncthreads();
  if (tid == 0) {
    float mu = 0.f;
    for (int i = 0; i < NMAT; ++i) mu += lA[i * 65];
    red[256] = mu * (1.0f / NMAT);
  }
  __syncthreads();
  const float mu = red[256];
  float ss = 0.f;
#pragma unroll
  for (int j = 0; j < 4; ++j) {
    int base = j * 1024 + tid * 4;
    float4 v = *reinterpret_cast<const float4*>(lA + base);
    float4 idm = id4(base);
    v.x -= mu * idm.x;
    v.y -= mu * idm.y;
    v.z -= mu * idm.z;
    v.w -= mu * idm.w;
    ss += v.x * v.x + v.y * v.y + v.z * v.z + v.w * v.w;
    *reinterpret_cast<float4*>(lA + base) = v;
  }
  red[tid] = ss;
  __syncthreads();
  for (int off = 128; off > 0; off >>= 1) {
    if (tid < off) red[tid] += red[tid + off];
    __syncthreads();
  }
  float nrm = sqrtf(red[0]);
  int s = 0;
  while (nrm > 0.25f && s < 12) {
    nrm *= 0.5f;
    s++;
  }
  const float dscale = exp2f((float)-s);
#pragma unroll
  for (int j = 0; j < 4; ++j) {
    int base = j * 1024 + tid * 4;
    float4 v = *reinterpret_cast<const float4*>(lA + base);
    v.x *= dscale;
    v.y *= dscale;
    v.z *= dscale;
    v.w *= dscale;
    *reinterpret_cast<float4*>(lA + base) = v;
    float4 idm = id4(base);
    *reinterpret_cast<float4*>(lY + base) =
        make_float4(idm.x + v.x * 0.125f, idm.y + v.y * 0.125f,
                    idm.z + v.z * 0.125f, idm.w + v.w * 0.125f);
  }
  __syncthreads();
  float p[4][4];
  for (int j = 7; j >= 1; --j) {
    mm64T(lA, lY, rt, ct, p);
    __syncthreads();
    float w[4][4];
    const float rj = 1.0f / (float)j;
#pragma unroll
    for (int i = 0; i < 4; ++i)
#pragma unroll
      for (int jj = 0; jj < 4; ++jj)
        w[i][jj] =
            p[i][jj] * rj + (((rt * 4 + i) == (ct * 4 + jj)) ? 1.0f : 0.0f);
    storeTile(lY, rt, ct, w);
    __syncthreads();
  }
  for (int tq = 0; tq < s; ++tq) {
    mm64T(lY, lY, rt, ct, p);
    __syncthreads();
    storeTile(lY, rt, ct, p);
    __syncthreads();
  }
  const float emu = expf(mu);
#pragma unroll
  for (int j = 0; j < 4; ++j) {
    int base = j * 1024 + tid * 4;
    float4 v = *reinterpret_cast<const float4*>(lY + base);
    v.x *= emu;
    v.y *= emu;
    v.z *= emu;
    v.w *= emu;
    *reinterpret_cast<float4*>(lY + base) = v;
  }
  __syncthreads();
  loadMat(lZ, ws + GS_OFF, tid);
  __syncthreads();
  mm64T(lY, lZ, rt, ct, p);  // E Gs
  __syncthreads();
  storeTile(lW, rt, ct, p);
  __syncthreads();
  mm64T(lZ, lW, rt, ct, p);  // G1 = Gs E Gs
  __syncthreads();
  storeTile(lA, rt, ct, p);
  __syncthreads();
  float qq[4][4];
#pragma unroll
  for (int i = 0; i < 4; ++i)
#pragma unroll
    for (int j = 0; j < 4; ++j)
      qq[i][j] = 0.5f * (p[i][j] + lA[(ct * 4 + j) * NMAT + rt * 4 + i]);
  __syncthreads();
  storeTile(lA, rt, ct, qq);
  __syncthreads();
  float c = block_ns(lA, lY, lZ, lW, red, NS_ITERS_MEAN);
  const float rs = 1.0f / sqrtf(c);
#pragma unroll
  for (int j = 0; j < 4; ++j) {  // Gis1 -> lY
    int base = j * 1024 + tid * 4;
    float4 v = *reinterpret_cast<const float4*>(lZ + base);
    *reinterpret_cast<float4*>(lY + base) =
        make_float4(v.x * rs, v.y * rs, v.z * rs, v.w * rs);
  }
  __syncthreads();
  loadMat(lZ, ws + BS_OFF, tid);
  __syncthreads();
  mm64T(lZ, lY, rt, ct, p);  // C = Bs Gis1
#pragma unroll
  for (int i = 0; i < 4; ++i)
#pragma unroll
    for (int j = 0; j < 4; ++j)
      ws[C_OFF + (rt * 4 + i) * NMAT + ct * 4 + j] = p[i][j];
}

// ============================ K5: out = C X C^T (MFMA) ======================
// 1024 threads = 4 chains, grid 256 (1 block/CU, 16 waves), waves_per_eu(4,4)
// for the 128-VGPR budget. C^T staged once per block into a shared LDS pair.
// 2 LDS arrays per chain: X then P' time-share (A0,A1) with one extra barrier.
// mm1: P' = X*C^T (A = X frags, B = C^T frags); mm2: O = C*P'.
__global__ __launch_bounds__(1024)
__attribute__((amdgpu_waves_per_eu(4, 4))) void k5_out_mfma(
    const float* __restrict__ x, const float* __restrict__ ws,
    float* __restrict__ out) {
  __shared__ __align__(16) short CtH[GSTR * 8], CtL[GSTR * 8];
  __shared__ __align__(16) short SH[K3_CHAINS][2][GSTR * 8];
  const int tid = threadIdx.x;
  const int ch = tid >> 8;
  const int ct = tid & 255;
  const int w4 = ct >> 6;
  const int R = w4 >> 1, Cb = w4 & 1;
  const int lane = tid & 63;
  const int ln = lane & 31, q = lane >> 5;
  const int col = 32 * Cb + ln;
  short* A0 = SH[ch][0];
  short* A1 = SH[ch][1];

  if (ch == 0) stageT(ws + C_OFF, CtH, CtL, ct);  // arr(k,n) = C[n][k]
  __syncthreads();

  for (int it = 0; it < CHAIN_MATS; ++it) {
    const int mat = blockIdx.x * (K3_CHAINS * CHAIN_MATS) + ch * CHAIN_MATS + it;
    stageT(x + (size_t)mat * MSIZE, A0, A1, ct);
    __syncthreads();
    floatx16 acc;
#pragma unroll
    for (int r = 0; r < 16; ++r) acc[r] = 0.0f;
#pragma unroll
    for (int kb = 0; kb < 4; ++kb) {
      bf16x8 axh = readFrag(A0, kb, q, 32 * R + ln);
      bf16x8 axl = readFrag(A1, kb, q, 32 * R + ln);
      bf16x8 cbh = readFrag(CtH, kb, q, col);  // B-op C^T
      bf16x8 cbl = readFrag(CtL, kb, q, col);
      acc = MFMA(axl, cbh, acc);
      acc = MFMA(axh, cbl, acc);
      acc = MFMA(axh, cbh, acc);
    }
    __syncthreads();  // all waves finished reading X
    float tmp[16];
#pragma unroll
    for (int r = 0; r < 16; ++r) tmp[r] = acc[r];
    storeChl(A0, A1, tmp, R, col, q);  // P' overwrites X
    __syncthreads();
#pragma unroll
    for (int r = 0; r < 16; ++r) acc[r] = 0.0f;
#pragma unroll
    for (int kb = 0; kb < 4; ++kb) {
      bf16x8 cah = readFrag(CtH, kb, q, 32 * R + ln);  // A-op C
      bf16x8 cal = readFrag(CtL, kb, q, 32 * R + ln);
      bf16x8 bph = readFrag(A0, kb, q, col);
      bf16x8 bpl = readFrag(A1, kb, q, col);
      acc = MFMA(cal, bph, acc);
      acc = MFMA(cah, bpl, acc);
      acc = MFMA(cah, bph, acc);
    }
    float* dst = out + (size_t)mat * MSIZE;
#pragma unroll
    for (int r = 0; r < 16; ++r) {
      int row = 32 * R + (r & 3) + 8 * (r >> 2) + 4 * q;
      dst[row * 64 + col] = acc[r];
    }
    __syncthreads();
  }
}

extern "C" void kernel_launch(void* const* d_in, const int* in_sizes, int n_in,
                              void* d_out, int out_size, void* d_ws,
                              size_t ws_size, hipStream_t stream) {
  const float* x = (const float*)d_in[0];
  const float* bias = (const float*)d_in[1];
  float* out = (float*)d_out;
  float* ws = (float*)d_ws;
  const float invB = 1.0f / (float)BATCH;
  float* red1 = out + (size_t)RED1_SLOT * MSIZE;  // 64 stage-1 slots in out

  k1_mean_bias<<<NBLK_RED + 1, 256, 0, stream>>>(x, bias, ws, out);
  k_reduce_parts<<<dim3(4, 32), 256, 0, stream>>>(out, red1, NBLK_RED, 1.0f);
  k_reduce_parts<<<dim3(4, 1), 256, 0, stream>>>(red1, ws + G_OFF, 32, invB);
  k2_mean_ns<<<1, 256, 0, stream>>>(ws);
  k3_logsum_mfma<<<NBLK_K3, 1024, 0, stream>>>(x, ws, out);
  k_reduce_parts<<<dim3(4, 64), 256, 0, stream>>>(out, red1,
                                                  NBLK_K3 * K3_CHAINS, 1.0f);
  k_reduce_parts<<<dim3(4, 1), 256, 0, stream>>>(red1, ws + MBAR_OFF, 64, invB);
  k4_center<<<1, 256, 0, stream>>>(ws);
  k5_out_mfma<<<NBLK_K5, 1024, 0, stream>>>(x, ws, out);
}

// Round 7
// 774.834 us; speedup vs baseline: 1.0315x; 1.0315x over previous
//
#include <hip/hip_runtime.h>

// ---------------------------------------------------------------------------
// SPDBatchNormMean forward, B=8192, n=64, fp32. Eigendecomp-free:
//   G0 = mean(x); Gs/Gis = G0^{±1/2} (Newton-Schulz); M = mean log(Gis x Gis)
//   (deg-18 Chebyshev on [0.3,4.0]); G1 = Gs expm(M) Gs; Gis1 = G1^{-1/2};
//   C = Bs Gis1 (Bs = bias^{1/2}); out = C x C^T.
// Round 9: kill the k3 spills (3rd attempt, two levers).
//  (a) k3/k5 use the explicit attribute pair amdgpu_flat_work_group_size
//      (1024,1024) + amdgpu_waves_per_eu(4,4) INSTEAD of __launch_bounds__
//      (whose macro expansion silently overrode waves_per_eu in r7/r8 ->
//      allocator stuck at 64 VGPR, ~300MB spill traffic/dispatch).
//  (b) recurrence state cut from 3 fp32[16] arrays + shifts to 2 in-place
//      arrays (pOdd/pEven, odd/even k steps consume+overwrite their own
//      parity; k-loop unrolled in pairs so indexing is static). Numerically
//      identical; ~16 fewer live VGPRs, no copy shuffles.
// ---------------------------------------------------------------------------

#define BATCH 8192
#define NMAT 64
#define MSIZE 4096
#define NBLK_RED 512
#define NBLK_K3 256
#define K3_CHAINS 4
#define CHAIN_MATS 8
#define NBLK_K5 256
#define DEG 18
#define CHEB_LO 0.30f
#define CHEB_HI 4.00f
#define NS_ITERS_MEAN 10
#define NS_ITERS_BIAS 12
#define GSTR 520 /* padded k-group stride (65*8 elems, 16B-aligned) */

// workspace layout (floats): only the 6 small matrices (96 KB).
#define G_OFF 0
#define BS_OFF (G_OFF + MSIZE)
#define GS_OFF (BS_OFF + MSIZE)
#define GIS_OFF (GS_OFF + MSIZE)
#define MBAR_OFF (GIS_OFF + MSIZE)
#define C_OFF (MBAR_OFF + MSIZE)
// scratch staged in `out` (128 MB, dead until k5): partial slots [0,1024),
// stage-1 reduce slots at [RED1_SLOT, RED1_SLOT+64).
#define RED1_SLOT 2048

typedef __attribute__((ext_vector_type(8))) short bf16x8;
typedef __attribute__((ext_vector_type(16))) float floatx16;
#define MFMA(a, b, c) __builtin_amdgcn_mfma_f32_32x32x16_bf16(a, b, c, 0, 0, 0)

__device__ __forceinline__ short f2bf(float x) {
  union {
    __bf16 b;
    short s;
  } u;
  u.b = (__bf16)x;  // hardware cvt, RNE
  return u.s;
}
__device__ __forceinline__ float bf2f(short h) {
  return __uint_as_float(((unsigned)(unsigned short)h) << 16);
}

// Stage a row-major 64x64 fp32 global matrix M into hi/lo bf16 LDS arrays in
// B-layout holding M^T: arr(k,n) = M[n][k]. 256 threads (st), packed b64.
__device__ __forceinline__ void stageT(const float* __restrict__ src, short* ah,
                                       short* al, int st) {
#pragma unroll
  for (int jb = 0; jb < 4; ++jb) {
    int flat = jb * 1024 + st * 4;
    float4 v = *reinterpret_cast<const float4*>(src + flat);
    int i = flat >> 6;   // row of M
    int j0 = flat & 63;  // col base (multiple of 4)
    int addr = (j0 >> 3) * GSTR + i * 8 + (j0 & 7);
    short4 h, l;
    h.x = f2bf(v.x); l.x = f2bf(v.x - bf2f(h.x));
    h.y = f2bf(v.y); l.y = f2bf(v.y - bf2f(h.y));
    h.z = f2bf(v.z); l.z = f2bf(v.z - bf2f(h.z));
    h.w = f2bf(v.w); l.w = f2bf(v.w - bf2f(h.w));
    *reinterpret_cast<short4*>(ah + addr) = h;
    *reinterpret_cast<short4*>(al + addr) = l;
  }
}

// Fragment read: returns elements j=0..7 at k = kb*16 + q*8 + j, column n.
__device__ __forceinline__ bf16x8 readFrag(const short* a, int kb, int q,
                                           int n) {
  return *reinterpret_cast<const bf16x8*>(a + (kb * 2 + q) * GSTR + n * 8);
}

// Store 16 C/D-layout fp32 regs into B-layout array(s) as bf16 (direct:
// arr(k=row, n=col) = v). Packs 4 consecutive rows per b64 write.
__device__ __forceinline__ void storeChi(short* dh, const float* v, int R,
                                         int col, int q) {
#pragma unroll
  for (int g4 = 0; g4 < 4; ++g4) {
    int addr = (4 * R + g4) * GSTR + col * 8 + 4 * q;
    short4 h;
    h.x = f2bf(v[4 * g4 + 0]);
    h.y = f2bf(v[4 * g4 + 1]);
    h.z = f2bf(v[4 * g4 + 2]);
    h.w = f2bf(v[4 * g4 + 3]);
    *reinterpret_cast<short4*>(dh + addr) = h;
  }
}
__device__ __forceinline__ void storeChl(short* dh, short* dl, const float* v,
                                         int R, int col, int q) {
#pragma unroll
  for (int g4 = 0; g4 < 4; ++g4) {
    int addr = (4 * R + g4) * GSTR + col * 8 + 4 * q;
    short4 h, l;
    float a0 = v[4 * g4 + 0], a1 = v[4 * g4 + 1];
    float a2 = v[4 * g4 + 2], a3 = v[4 * g4 + 3];
    h.x = f2bf(a0); l.x = f2bf(a0 - bf2f(h.x));
    h.y = f2bf(a1); l.y = f2bf(a1 - bf2f(h.y));
    h.z = f2bf(a2); l.z = f2bf(a2 - bf2f(h.z));
    h.w = f2bf(a3); l.w = f2bf(a3 - bf2f(h.w));
    *reinterpret_cast<short4*>(dh + addr) = h;
    *reinterpret_cast<short4*>(dl + addr) = l;
  }
}

// ============================ vector-ALU helpers (k1/k2/k4) ================

__device__ __forceinline__ void mm64T(const float* __restrict__ A,
                                      const float* __restrict__ B, int rt,
                                      int ct, float p[4][4]) {
#pragma unroll
  for (int i = 0; i < 4; ++i)
#pragma unroll
    for (int j = 0; j < 4; ++j) p[i][j] = 0.0f;
#pragma unroll 4
  for (int k = 0; k < NMAT; ++k) {
    float4 a = *reinterpret_cast<const float4*>(A + k * NMAT + rt * 4);
    float4 b = *reinterpret_cast<const float4*>(B + k * NMAT + ct * 4);
    p[0][0] = fmaf(a.x, b.x, p[0][0]);
    p[0][1] = fmaf(a.x, b.y, p[0][1]);
    p[0][2] = fmaf(a.x, b.z, p[0][2]);
    p[0][3] = fmaf(a.x, b.w, p[0][3]);
    p[1][0] = fmaf(a.y, b.x, p[1][0]);
    p[1][1] = fmaf(a.y, b.y, p[1][1]);
    p[1][2] = fmaf(a.y, b.z, p[1][2]);
    p[1][3] = fmaf(a.y, b.w, p[1][3]);
    p[2][0] = fmaf(a.z, b.x, p[2][0]);
    p[2][1] = fmaf(a.z, b.y, p[2][1]);
    p[2][2] = fmaf(a.z, b.z, p[2][2]);
    p[2][3] = fmaf(a.z, b.w, p[2][3]);
    p[3][0] = fmaf(a.w, b.x, p[3][0]);
    p[3][1] = fmaf(a.w, b.y, p[3][1]);
    p[3][2] = fmaf(a.w, b.z, p[3][2]);
    p[3][3] = fmaf(a.w, b.w, p[3][3]);
  }
}

__device__ __forceinline__ void storeTile(float* dst, int rt, int ct,
                                          const float p[4][4]) {
#pragma unroll
  for (int i = 0; i < 4; ++i)
    *reinterpret_cast<float4*>(dst + (rt * 4 + i) * NMAT + ct * 4) =
        make_float4(p[i][0], p[i][1], p[i][2], p[i][3]);
}

__device__ __forceinline__ void loadMat(float* dst,
                                        const float* __restrict__ src,
                                        int tid) {
#pragma unroll
  for (int j = 0; j < 4; ++j)
    *reinterpret_cast<float4*>(dst + j * 1024 + tid * 4) =
        *reinterpret_cast<const float4*>(src + j * 1024 + tid * 4);
}

__device__ __forceinline__ float4 id4(int base) {
  return make_float4(((base + 0) % 65) == 0 ? 1.f : 0.f,
                     ((base + 1) % 65) == 0 ? 1.f : 0.f,
                     ((base + 2) % 65) == 0 ? 1.f : 0.f,
                     ((base + 3) % 65) == 0 ? 1.f : 0.f);
}

__device__ float block_ns(const float* lA, float* lY, float* lZ, float* lW,
                          float* red, int iters) {
  const int tid = threadIdx.x;
  const int rt = tid >> 4, ct = tid & 15;
  float ss = 0.0f;
#pragma unroll
  for (int j = 0; j < 4; ++j) {
    float4 v = *reinterpret_cast<const float4*>(lA + j * 1024 + tid * 4);
    ss += v.x * v.x + v.y * v.y + v.z * v.z + v.w * v.w;
  }
  red[tid] = ss;
  __syncthreads();
  for (int off = 128; off > 0; off >>= 1) {
    if (tid < off) red[tid] += red[tid + off];
    __syncthreads();
  }
  const float c = sqrtf(red[0] * 0.5f);
  const float rc = 1.0f / c;
#pragma unroll
  for (int j = 0; j < 4; ++j) {
    int base = j * 1024 + tid * 4;
    float4 v = *reinterpret_cast<const float4*>(lA + base);
    v.x *= rc;
    v.y *= rc;
    v.z *= rc;
    v.w *= rc;
    *reinterpret_cast<float4*>(lY + base) = v;
    *reinterpret_cast<float4*>(lZ + base) = id4(base);
  }
  __syncthreads();
  for (int it = 0; it < iters; ++it) {
    float p[4][4];
    mm64T(lZ, lY, rt, ct, p);
    float w[4][4];
#pragma unroll
    for (int i = 0; i < 4; ++i)
#pragma unroll
      for (int j = 0; j < 4; ++j)
        w[i][j] = ((rt * 4 + i) == (ct * 4 + j) ? 1.5f : 0.0f) - 0.5f * p[i][j];
    storeTile(lW, rt, ct, w);
    __syncthreads();
    float py[4][4], pz[4][4];
    mm64T(lY, lW, rt, ct, py);
    mm64T(lW, lZ, rt, ct, pz);
    __syncthreads();
    storeTile(lY, rt, ct, py);
    storeTile(lZ, rt, ct, pz);
    __syncthreads();
  }
  return c;
}

// K1: blocks [0,NBLK_RED) partial-sum x into `pg` (out scratch); block
// NBLK_RED does Bs = bias^{1/2}.
__global__ __launch_bounds__(256) void k1_mean_bias(
    const float* __restrict__ x, const float* __restrict__ bias,
    float* __restrict__ ws, float* __restrict__ pg) {
  const int tid = threadIdx.x;
  if (blockIdx.x < NBLK_RED) {
    float acc[16];
#pragma unroll
    for (int j = 0; j < 16; ++j) acc[j] = 0.f;
    for (int i = blockIdx.x; i < BATCH; i += NBLK_RED) {
      const float* src = x + (size_t)i * MSIZE;
#pragma unroll
      for (int j = 0; j < 4; ++j) {
        float4 v = *reinterpret_cast<const float4*>(src + j * 1024 + tid * 4);
        acc[j * 4 + 0] += v.x;
        acc[j * 4 + 1] += v.y;
        acc[j * 4 + 2] += v.z;
        acc[j * 4 + 3] += v.w;
      }
    }
    float* dst = pg + (size_t)blockIdx.x * MSIZE;
#pragma unroll
    for (int j = 0; j < 4; ++j)
      *reinterpret_cast<float4*>(dst + j * 1024 + tid * 4) = make_float4(
          acc[j * 4 + 0], acc[j * 4 + 1], acc[j * 4 + 2], acc[j * 4 + 3]);
  } else {
    __shared__ __align__(16) float lA[MSIZE], lY[MSIZE], lZ[MSIZE], lW[MSIZE];
    __shared__ float red[257];
    loadMat(lA, bias, tid);
    __syncthreads();
    float c = block_ns(lA, lY, lZ, lW, red, NS_ITERS_BIAS);
    float sc = sqrtf(c);
#pragma unroll
    for (int j = 0; j < 4; ++j) {
      int base = j * 1024 + tid * 4;
      float4 v = *reinterpret_cast<const float4*>(lY + base);
      v.x *= sc;
      v.y *= sc;
      v.z *= sc;
      v.w *= sc;
      *reinterpret_cast<float4*>(ws + BS_OFF + base) = v;
    }
  }
}

// Two-stage partial reduce. grid = (4, NY): block (bx, by) sums parts
// p = by, by+NY, ... for its 1 KB element range; writes slot `by` of dst.
__global__ __launch_bounds__(256) void k_reduce_parts(
    const float* __restrict__ src, float* __restrict__ dst, int nparts,
    float scale) {
  int e4 = blockIdx.x * 256 + threadIdx.x;
  float4 acc = make_float4(0.f, 0.f, 0.f, 0.f);
  for (int b = blockIdx.y; b < nparts; b += gridDim.y) {
    float4 v =
        *reinterpret_cast<const float4*>(src + (size_t)b * MSIZE + e4 * 4);
    acc.x += v.x;
    acc.y += v.y;
    acc.z += v.z;
    acc.w += v.w;
  }
  acc.x *= scale;
  acc.y *= scale;
  acc.z *= scale;
  acc.w *= scale;
  *reinterpret_cast<float4*>(dst + (size_t)blockIdx.y * MSIZE + e4 * 4) = acc;
}

__global__ __launch_bounds__(256) void k2_mean_ns(float* __restrict__ ws) {
  __shared__ __align__(16) float lA[MSIZE], lY[MSIZE], lZ[MSIZE], lW[MSIZE];
  __shared__ float red[257];
  const int tid = threadIdx.x;
  loadMat(lA, ws + G_OFF, tid);
  __syncthreads();
  float c = block_ns(lA, lY, lZ, lW, red, NS_ITERS_MEAN);
  float sc = sqrtf(c), rs = 1.0f / sqrtf(c);
#pragma unroll
  for (int j = 0; j < 4; ++j) {
    int base = j * 1024 + tid * 4;
    float4 y = *reinterpret_cast<const float4*>(lY + base);
    float4 z = *reinterpret_cast<const float4*>(lZ + base);
    *reinterpret_cast<float4*>(ws + GS_OFF + base) =
        make_float4(y.x * sc, y.y * sc, y.z * sc, y.w * sc);
    *reinterpret_cast<float4*>(ws + GIS_OFF + base) =
        make_float4(z.x * rs, z.y * rs, z.z * rs, z.w * rs);
  }
}

// ============================ K3: MFMA Chebyshev log-sum ====================
// 1024 threads = 4 independent 4-wave chains; grid 256 (1 block/CU, 16 waves).
// Explicit amdgpu attributes (NOT __launch_bounds__, whose macro overrode
// waves_per_eu in r7/r8): flat_work_group_size(1024,1024) pins block size;
// waves_per_eu(4,4) clamps occupancy at 4 waves/EU -> VGPR budget 128.
// Recurrence keeps only pOdd/pEven (in-place parity update, pair-unrolled).
__global__ __attribute__((amdgpu_flat_work_group_size(1024, 1024),
                          amdgpu_waves_per_eu(4, 4))) void
k3_logsum_mfma(const float* __restrict__ x, const float* __restrict__ ws,
               float* __restrict__ pm) {
  __shared__ __align__(16) short GisH[GSTR * 8], GisL[GSTR * 8];
  __shared__ __align__(16) short SH[K3_CHAINS][3][GSTR * 8];
  const int tid = threadIdx.x;
  const int ch = tid >> 8;   // chain 0..3
  const int ct = tid & 255;  // thread within chain
  const int w4 = ct >> 6;    // wave within chain
  const int R = w4 >> 1, Cb = w4 & 1;
  const int lane = tid & 63;
  const int ln = lane & 31, q = lane >> 5;
  const int col = 32 * Cb + ln;
  short* A0 = SH[ch][0];
  short* A1 = SH[ch][1];
  short* A2 = SH[ch][2];

  const float m = 0.5f * (CHEB_LO + CHEB_HI), hh = 0.5f * (CHEB_HI - CHEB_LO);
  const float invh = 1.0f / hh;
  const float beta = hh / m;
  const float zeta = (1.0f - sqrtf(1.0f - beta * beta)) / beta;
  const float ca0 = logf(m) - log1pf(zeta * zeta);
  const float ca1 = 2.0f * zeta;

  // diagonal index: r_dg = r for which row(r)==col (or -1). row(r) =
  // 32R + (r&3) + 8(r>>2) + 4q.
  int d = col - 32 * R - 4 * q;
  const int r_dg =
      (d >= 0 && d < 32 && (d & 4) == 0) ? ((d >> 3) * 4 + (d & 3)) : -1;

  if (ch == 0) stageT(ws + GIS_OFF, GisH, GisL, ct);
  __syncthreads();

  float Mac[16];
#pragma unroll
  for (int r = 0; r < 16; ++r) Mac[r] = 0.0f;

  for (int it = 0; it < CHAIN_MATS; ++it) {
    const int mat = blockIdx.x * (K3_CHAINS * CHAIN_MATS) + ch * CHAIN_MATS + it;
    stageT(x + (size_t)mat * MSIZE, A0, A1, ct);
    __syncthreads();
    // mm1: P0 = X * Gis   (A = X frags from A0/A1, B = Gis shared)
    floatx16 acc;
#pragma unroll
    for (int r = 0; r < 16; ++r) acc[r] = 0.0f;
#pragma unroll
    for (int kb = 0; kb < 4; ++kb) {
      bf16x8 axh = readFrag(A0, kb, q, 32 * R + ln);
      bf16x8 axl = readFrag(A1, kb, q, 32 * R + ln);
      bf16x8 gbh = readFrag(GisH, kb, q, col);
      bf16x8 gbl = readFrag(GisL, kb, q, col);
      acc = MFMA(axl, gbh, acc);
      acc = MFMA(axh, gbl, acc);
      acc = MFMA(axh, gbh, acc);
    }
    __syncthreads();  // all waves finished reading X from A0/A1
    float tmp[16];
#pragma unroll
    for (int r = 0; r < 16; ++r) tmp[r] = acc[r];
    storeChl(A0, A1, tmp, R, col, q);  // P0 overwrites X
    __syncthreads();
    // mm2: S = Gis * P0 -> U = (S - mI)/h
#pragma unroll
    for (int r = 0; r < 16; ++r) acc[r] = 0.0f;
#pragma unroll
    for (int kb = 0; kb < 4; ++kb) {
      bf16x8 gah = readFrag(GisH, kb, q, 32 * R + ln);
      bf16x8 gal = readFrag(GisL, kb, q, 32 * R + ln);
      bf16x8 bph = readFrag(A0, kb, q, col);
      bf16x8 bpl = readFrag(A1, kb, q, col);
      acc = MFMA(gal, bph, acc);
      acc = MFMA(gah, bpl, acc);
      acc = MFMA(gah, bph, acc);
    }
    // pOdd = U (=T1); Mac += ca0*I + ca1*T1
    float pOdd[16], pEven[16];
#pragma unroll
    for (int r = 0; r < 16; ++r) {
      float dgr = (r == r_dg) ? 1.0f : 0.0f;
      pOdd[r] = (acc[r] - m * dgr) * invh;
      Mac[r] += ca0 * dgr + ca1 * pOdd[r];
    }
    __syncthreads();  // all waves finished reading P0 from A0/A1
    storeChl(A0, A1, pOdd, R, col, q);  // U overwrites P0
    __syncthreads();
    bf16x8 uh[4], ul[4];
#pragma unroll
    for (int kb = 0; kb < 4; ++kb) {  // A-op U via symmetry -> registers
      uh[kb] = readFrag(A0, kb, q, 32 * R + ln);
      ul[kb] = readFrag(A1, kb, q, 32 * R + ln);
    }
    // k = 2: pEven = T2 = 2 U*U - I (B-op U from A0/A1, hi/lo)
#pragma unroll
    for (int r = 0; r < 16; ++r) acc[r] = 0.0f;
#pragma unroll
    for (int kb = 0; kb < 4; ++kb) {
      bf16x8 buh = readFrag(A0, kb, q, col);
      bf16x8 bul = readFrag(A1, kb, q, col);
      acc = MFMA(ul[kb], buh, acc);
      acc = MFMA(uh[kb], bul, acc);
      acc = MFMA(uh[kb], buh, acc);
    }
    float zk = zeta * zeta;
#pragma unroll
    for (int r = 0; r < 16; ++r) {
      float dgr = (r == r_dg) ? 1.0f : 0.0f;
      pEven[r] = 2.0f * acc[r] - dgr;
      Mac[r] += -zk * pEven[r];  // ak(k=2) = -2*zk/2
    }
    storeChi(A2, pEven, R, col, q);  // T2 -> A2
    __syncthreads();
    // k = 3..DEG in pairs: odd k consumes+overwrites pOdd (B-op from A2,
    // store to A0); even k consumes+overwrites pEven (B-op from A0, store
    // to A2). In-place: T_k = 2 U T_{k-1} - T_{k-2} with T_{k-2} of same
    // parity. U stays in registers; A1's U-lo copy is dead after k=2.
    for (int kk = 3; kk < DEG; kk += 2) {
      // odd step k = kk
#pragma unroll
      for (int r = 0; r < 16; ++r) acc[r] = 0.0f;
#pragma unroll
      for (int kb = 0; kb < 4; ++kb) {
        bf16x8 b = readFrag(A2, kb, q, col);
        acc = MFMA(ul[kb], b, acc);
        acc = MFMA(uh[kb], b, acc);
      }
      zk *= -zeta;
      {
        float ak = -2.0f * zk / (float)kk;
#pragma unroll
        for (int r = 0; r < 16; ++r) {
          pOdd[r] = 2.0f * acc[r] - pOdd[r];
          Mac[r] += ak * pOdd[r];
        }
      }
      storeChi(A0, pOdd, R, col, q);  // kk <= DEG-1, always needed
      __syncthreads();
      // even step k = kk+1
#pragma unroll
      for (int r = 0; r < 16; ++r) acc[r] = 0.0f;
#pragma unroll
      for (int kb = 0; kb < 4; ++kb) {
        bf16x8 b = readFrag(A0, kb, q, col);
        acc = MFMA(ul[kb], b, acc);
        acc = MFMA(uh[kb], b, acc);
      }
      zk *= -zeta;
      {
        float ak = -2.0f * zk / (float)(kk + 1);
#pragma unroll
        for (int r = 0; r < 16; ++r) {
          pEven[r] = 2.0f * acc[r] - pEven[r];
          Mac[r] += ak * pEven[r];
        }
      }
      if (kk + 1 < DEG) storeChi(A2, pEven, R, col, q);
      __syncthreads();
    }
  }
  // per-chain partial (1024 total)
  float* dst = pm + (size_t)(blockIdx.x * K3_CHAINS + ch) * MSIZE;
#pragma unroll
  for (int r = 0; r < 16; ++r) {
    int row = 32 * R + (r & 3) + 8 * (r >> 2) + 4 * q;
    dst[row * 64 + col] = Mac[r];
  }
}

// K4: E = expm(Mbar); G1 = Gs E Gs; Gis1 = sym(G1)^{-1/2}; C = Bs Gis1 -> ws.
__global__ __launch_bounds__(256) void k4_center(float* __restrict__ ws) {
  __shared__ __align__(16) float lA[MSIZE], lY[MSIZE], lZ[MSIZE], lW[MSIZE];
  __shared__ float red[257];
  const int tid = threadIdx.x;
  const int rt = tid >> 4, ct = tid & 15;
  loadMat(lA, ws + MBAR_OFF, tid);
  __syncthreads();
  if (tid == 0) {
    float mu = 0.f;
    for (int i = 0; i < NMAT; ++i) mu += lA[i * 65];
    red[256] = mu * (1.0f / NMAT);
  }
  __syncthreads();
  const float mu = red[256];
  float ss = 0.f;
#pragma unroll
  for (int j = 0; j < 4; ++j) {
    int base = j * 1024 + tid * 4;
    float4 v = *reinterpret_cast<const float4*>(lA + base);
    float4 idm = id4(base);
    v.x -= mu * idm.x;
    v.y -= mu * idm.y;
    v.z -= mu * idm.z;
    v.w -= mu * idm.w;
    ss += v.x * v.x + v.y * v.y + v.z * v.z + v.w * v.w;
    *reinterpret_cast<float4*>(lA + base) = v;
  }
  red[tid] = ss;
  __syncthreads();
  for (int off = 128; off > 0; off >>= 1) {
    if (tid < off) red[tid] += red[tid + off];
    __syncthreads();
  }
  float nrm = sqrtf(red[0]);
  int s = 0;
  while (nrm > 0.25f && s < 12) {
    nrm *= 0.5f;
    s++;
  }
  const float dscale = exp2f((float)-s);
#pragma unroll
  for (int j = 0; j < 4; ++j) {
    int base = j * 1024 + tid * 4;
    float4 v = *reinterpret_cast<const float4*>(lA + base);
    v.x *= dscale;
    v.y *= dscale;
    v.z *= dscale;
    v.w *= dscale;
    *reinterpret_cast<float4*>(lA + base) = v;
    float4 idm = id4(base);
    *reinterpret_cast<float4*>(lY + base) =
        make_float4(idm.x + v.x * 0.125f, idm.y + v.y * 0.125f,
                    idm.z + v.z * 0.125f, idm.w + v.w * 0.125f);
  }
  __syncthreads();
  float p[4][4];
  for (int j = 7; j >= 1; --j) {
    mm64T(lA, lY, rt, ct, p);
    __syncthreads();
    float w[4][4];
    const float rj = 1.0f / (float)j;
#pragma unroll
    for (int i = 0; i < 4; ++i)
#pragma unroll
      for (int jj = 0; jj < 4; ++jj)
        w[i][jj] =
            p[i][jj] * rj + (((rt * 4 + i) == (ct * 4 + jj)) ? 1.0f : 0.0f);
    storeTile(lY, rt, ct, w);
    __syncthreads();
  }
  for (int tq = 0; tq < s; ++tq) {
    mm64T(lY, lY, rt, ct, p);
    __syncthreads();
    storeTile(lY, rt, ct, p);
    __syncthreads();
  }
  const float emu = expf(mu);
#pragma unroll
  for (int j = 0; j < 4; ++j) {
    int base = j * 1024 + tid * 4;
    float4 v = *reinterpret_cast<const float4*>(lY + base);
    v.x *= emu;
    v.y *= emu;
    v.z *= emu;
    v.w *= emu;
    *reinterpret_cast<float4*>(lY + base) = v;
  }
  __syncthreads();
  loadMat(lZ, ws + GS_OFF, tid);
  __syncthreads();
  mm64T(lY, lZ, rt, ct, p);  // E Gs
  __syncthreads();
  storeTile(lW, rt, ct, p);
  __syncthreads();
  mm64T(lZ, lW, rt, ct, p);  // G1 = Gs E Gs
  __syncthreads();
  storeTile(lA, rt, ct, p);
  __syncthreads();
  float qq[4][4];
#pragma unroll
  for (int i = 0; i < 4; ++i)
#pragma unroll
    for (int j = 0; j < 4; ++j)
      qq[i][j] = 0.5f * (p[i][j] + lA[(ct * 4 + j) * NMAT + rt * 4 + i]);
  __syncthreads();
  storeTile(lA, rt, ct, qq);
  __syncthreads();
  float c = block_ns(lA, lY, lZ, lW, red, NS_ITERS_MEAN);
  const float rs = 1.0f / sqrtf(c);
#pragma unroll
  for (int j = 0; j < 4; ++j) {  // Gis1 -> lY
    int base = j * 1024 + tid * 4;
    float4 v = *reinterpret_cast<const float4*>(lZ + base);
    *reinterpret_cast<float4*>(lY + base) =
        make_float4(v.x * rs, v.y * rs, v.z * rs, v.w * rs);
  }
  __syncthreads();
  loadMat(lZ, ws + BS_OFF, tid);
  __syncthreads();
  mm64T(lZ, lY, rt, ct, p);  // C = Bs Gis1
#pragma unroll
  for (int i = 0; i < 4; ++i)
#pragma unroll
    for (int j = 0; j < 4; ++j)
      ws[C_OFF + (rt * 4 + i) * NMAT + ct * 4 + j] = p[i][j];
}

// ============================ K5: out = C X C^T (MFMA) ======================
// 1024 threads = 4 chains, grid 256 (1 block/CU, 16 waves), explicit amdgpu
// attributes as in k3. C^T staged once per block into a shared LDS pair.
// 2 LDS arrays per chain: X then P' time-share (A0,A1) with one extra barrier.
// mm1: P' = X*C^T (A = X frags, B = C^T frags); mm2: O = C*P'.
__global__ __attribute__((amdgpu_flat_work_group_size(1024, 1024),
                          amdgpu_waves_per_eu(4, 4))) void
k5_out_mfma(const float* __restrict__ x, const float* __restrict__ ws,
            float* __restrict__ out) {
  __shared__ __align__(16) short CtH[GSTR * 8], CtL[GSTR * 8];
  __shared__ __align__(16) short SH[K3_CHAINS][2][GSTR * 8];
  const int tid = threadIdx.x;
  const int ch = tid >> 8;
  const int ct = tid & 255;
  const int w4 = ct >> 6;
  const int R = w4 >> 1, Cb = w4 & 1;
  const int lane = tid & 63;
  const int ln = lane & 31, q = lane >> 5;
  const int col = 32 * Cb + ln;
  short* A0 = SH[ch][0];
  short* A1 = SH[ch][1];

  if (ch == 0) stageT(ws + C_OFF, CtH, CtL, ct);  // arr(k,n) = C[n][k]
  __syncthreads();

  for (int it = 0; it < CHAIN_MATS; ++it) {
    const int mat = blockIdx.x * (K3_CHAINS * CHAIN_MATS) + ch * CHAIN_MATS + it;
    stageT(x + (size_t)mat * MSIZE, A0, A1, ct);
    __syncthreads();
    floatx16 acc;
#pragma unroll
    for (int r = 0; r < 16; ++r) acc[r] = 0.0f;
#pragma unroll
    for (int kb = 0; kb < 4; ++kb) {
      bf16x8 axh = readFrag(A0, kb, q, 32 * R + ln);
      bf16x8 axl = readFrag(A1, kb, q, 32 * R + ln);
      bf16x8 cbh = readFrag(CtH, kb, q, col);  // B-op C^T
      bf16x8 cbl = readFrag(CtL, kb, q, col);
      acc = MFMA(axl, cbh, acc);
      acc = MFMA(axh, cbl, acc);
      acc = MFMA(axh, cbh, acc);
    }
    __syncthreads();  // all waves finished reading X
    float tmp[16];
#pragma unroll
    for (int r = 0; r < 16; ++r) tmp[r] = acc[r];
    storeChl(A0, A1, tmp, R, col, q);  // P' overwrites X
    __syncthreads();
#pragma unroll
    for (int r = 0; r < 16; ++r) acc[r] = 0.0f;
#pragma unroll
    for (int kb = 0; kb < 4; ++kb) {
      bf16x8 cah = readFrag(CtH, kb, q, 32 * R + ln);  // A-op C
      bf16x8 cal = readFrag(CtL, kb, q, 32 * R + ln);
      bf16x8 bph = readFrag(A0, kb, q, col);
      bf16x8 bpl = readFrag(A1, kb, q, col);
      acc = MFMA(cal, bph, acc);
      acc = MFMA(cah, bpl, acc);
      acc = MFMA(cah, bph, acc);
    }
    float* dst = out + (size_t)mat * MSIZE;
#pragma unroll
    for (int r = 0; r < 16; ++r) {
      int row = 32 * R + (r & 3) + 8 * (r >> 2) + 4 * q;
      dst[row * 64 + col] = acc[r];
    }
    __syncthreads();
  }
}

extern "C" void kernel_launch(void* const* d_in, const int* in_sizes, int n_in,
                              void* d_out, int out_size, void* d_ws,
                              size_t ws_size, hipStream_t stream) {
  const float* x = (const float*)d_in[0];
  const float* bias = (const float*)d_in[1];
  float* out = (float*)d_out;
  float* ws = (float*)d_ws;
  const float invB = 1.0f / (float)BATCH;
  float* red1 = out + (size_t)RED1_SLOT * MSIZE;  // 64 stage-1 slots in out

  k1_mean_bias<<<NBLK_RED + 1, 256, 0, stream>>>(x, bias, ws, out);
  k_reduce_parts<<<dim3(4, 32), 256, 0, stream>>>(out, red1, NBLK_RED, 1.0f);
  k_reduce_parts<<<dim3(4, 1), 256, 0, stream>>>(red1, ws + G_OFF, 32, invB);
  k2_mean_ns<<<1, 256, 0, stream>>>(ws);
  k3_logsum_mfma<<<NBLK_K3, 1024, 0, stream>>>(x, ws, out);
  k_reduce_parts<<<dim3(4, 64), 256, 0, stream>>>(out, red1,
                                                  NBLK_K3 * K3_CHAINS, 1.0f);
  k_reduce_parts<<<dim3(4, 1), 256, 0, stream>>>(red1, ws + MBAR_OFF, 64, invB);
  k4_center<<<1, 256, 0, stream>>>(ws);
  k5_out_mfma<<<NBLK_K5, 1024, 0, stream>>>(x, ws, out);
}

// Round 8
// 709.459 us; speedup vs baseline: 1.1266x; 1.0921x over previous
//
#include <hip/hip_runtime.h>

// ---------------------------------------------------------------------------
// SPDBatchNormMean forward, B=8192, n=64, fp32. Eigendecomp-free:
//   G0 = mean(x); Gs/Gis = G0^{±1/2} (Newton-Schulz); M = mean log(Gis x Gis)
//   (deg-18 Chebyshev on [0.3,4.0]); G1 = Gs expm(M) Gs; Gis1 = G1^{-1/2};
//   C = Bs Gis1 (Bs = bias^{1/2}); out = C x C^T.
// Round 10: fit k3's live arch-VGPR state under the hard 64 cap.
// Diagnosis: gfx950 unified VGPR/AGPR file = 512/wave-slot; 16-wave blocks
// -> 128 unified/wave, split 64 arch + 64 AGPR by the backend. No attribute
// raises arch past 64 (r7/r8/r9 all pinned at 64). So shrink live state:
//   - uh/ul register cache dropped (-32 VGPRs); U's A-op fragments re-read
//     from LDS each recurrence step. U stays resident in A0/A1: 4 LDS
//     arrays/chain (A0,A1 = X then U hi/lo; A2,A3 = P0 then T ping-pong).
//   - 3 chains x 256 threads = 768-thread blocks keeps 4-array layout at the
//     PROVEN 116,480 B LDS (the 146KB 4-chain variant crashed containers).
//     12 waves/CU; unified budget 170/wave; live ~58 < 64 -> no spills even
//     at a stubborn 64-arch split.
//   - matrices strided over 768 global chains (8192 = 768*10 + 512).
// Recurrence math identical to round 9 (pOdd/pEven in place).
// ---------------------------------------------------------------------------

#define BATCH 8192
#define NMAT 64
#define MSIZE 4096
#define NBLK_RED 512
#define NBLK_K3 256
#define K3_CHAINS 3
#define K5_CHAINS 4
#define CHAIN_MATS 8
#define NBLK_K5 256
#define DEG 18
#define CHEB_LO 0.30f
#define CHEB_HI 4.00f
#define NS_ITERS_MEAN 10
#define NS_ITERS_BIAS 12
#define GSTR 520 /* padded k-group stride (65*8 elems, 16B-aligned) */

// workspace layout (floats): only the 6 small matrices (96 KB).
#define G_OFF 0
#define BS_OFF (G_OFF + MSIZE)
#define GS_OFF (BS_OFF + MSIZE)
#define GIS_OFF (GS_OFF + MSIZE)
#define MBAR_OFF (GIS_OFF + MSIZE)
#define C_OFF (MBAR_OFF + MSIZE)
// scratch staged in `out` (128 MB, dead until k5): partial slots [0,768),
// stage-1 reduce slots at [RED1_SLOT, RED1_SLOT+64).
#define RED1_SLOT 2048

typedef __attribute__((ext_vector_type(8))) short bf16x8;
typedef __attribute__((ext_vector_type(16))) float floatx16;
#define MFMA(a, b, c) __builtin_amdgcn_mfma_f32_32x32x16_bf16(a, b, c, 0, 0, 0)

__device__ __forceinline__ short f2bf(float x) {
  union {
    __bf16 b;
    short s;
  } u;
  u.b = (__bf16)x;  // hardware cvt, RNE
  return u.s;
}
__device__ __forceinline__ float bf2f(short h) {
  return __uint_as_float(((unsigned)(unsigned short)h) << 16);
}

// Stage a row-major 64x64 fp32 global matrix M into hi/lo bf16 LDS arrays in
// B-layout holding M^T: arr(k,n) = M[n][k]. 256 threads (st), packed b64.
__device__ __forceinline__ void stageT(const float* __restrict__ src, short* ah,
                                       short* al, int st) {
#pragma unroll
  for (int jb = 0; jb < 4; ++jb) {
    int flat = jb * 1024 + st * 4;
    float4 v = *reinterpret_cast<const float4*>(src + flat);
    int i = flat >> 6;   // row of M
    int j0 = flat & 63;  // col base (multiple of 4)
    int addr = (j0 >> 3) * GSTR + i * 8 + (j0 & 7);
    short4 h, l;
    h.x = f2bf(v.x); l.x = f2bf(v.x - bf2f(h.x));
    h.y = f2bf(v.y); l.y = f2bf(v.y - bf2f(h.y));
    h.z = f2bf(v.z); l.z = f2bf(v.z - bf2f(h.z));
    h.w = f2bf(v.w); l.w = f2bf(v.w - bf2f(h.w));
    *reinterpret_cast<short4*>(ah + addr) = h;
    *reinterpret_cast<short4*>(al + addr) = l;
  }
}

// Fragment read: returns elements j=0..7 at k = kb*16 + q*8 + j, column n.
__device__ __forceinline__ bf16x8 readFrag(const short* a, int kb, int q,
                                           int n) {
  return *reinterpret_cast<const bf16x8*>(a + (kb * 2 + q) * GSTR + n * 8);
}

// Store 16 C/D-layout fp32 regs into B-layout array(s) as bf16 (direct:
// arr(k=row, n=col) = v). Packs 4 consecutive rows per b64 write.
__device__ __forceinline__ void storeChi(short* dh, const float* v, int R,
                                         int col, int q) {
#pragma unroll
  for (int g4 = 0; g4 < 4; ++g4) {
    int addr = (4 * R + g4) * GSTR + col * 8 + 4 * q;
    short4 h;
    h.x = f2bf(v[4 * g4 + 0]);
    h.y = f2bf(v[4 * g4 + 1]);
    h.z = f2bf(v[4 * g4 + 2]);
    h.w = f2bf(v[4 * g4 + 3]);
    *reinterpret_cast<short4*>(dh + addr) = h;
  }
}
__device__ __forceinline__ void storeChl(short* dh, short* dl, const float* v,
                                         int R, int col, int q) {
#pragma unroll
  for (int g4 = 0; g4 < 4; ++g4) {
    int addr = (4 * R + g4) * GSTR + col * 8 + 4 * q;
    short4 h, l;
    float a0 = v[4 * g4 + 0], a1 = v[4 * g4 + 1];
    float a2 = v[4 * g4 + 2], a3 = v[4 * g4 + 3];
    h.x = f2bf(a0); l.x = f2bf(a0 - bf2f(h.x));
    h.y = f2bf(a1); l.y = f2bf(a1 - bf2f(h.y));
    h.z = f2bf(a2); l.z = f2bf(a2 - bf2f(h.z));
    h.w = f2bf(a3); l.w = f2bf(a3 - bf2f(h.w));
    *reinterpret_cast<short4*>(dh + addr) = h;
    *reinterpret_cast<short4*>(dl + addr) = l;
  }
}

// ============================ vector-ALU helpers (k1/k2/k4) ================

__device__ __forceinline__ void mm64T(const float* __restrict__ A,
                                      const float* __restrict__ B, int rt,
                                      int ct, float p[4][4]) {
#pragma unroll
  for (int i = 0; i < 4; ++i)
#pragma unroll
    for (int j = 0; j < 4; ++j) p[i][j] = 0.0f;
#pragma unroll 4
  for (int k = 0; k < NMAT; ++k) {
    float4 a = *reinterpret_cast<const float4*>(A + k * NMAT + rt * 4);
    float4 b = *reinterpret_cast<const float4*>(B + k * NMAT + ct * 4);
    p[0][0] = fmaf(a.x, b.x, p[0][0]);
    p[0][1] = fmaf(a.x, b.y, p[0][1]);
    p[0][2] = fmaf(a.x, b.z, p[0][2]);
    p[0][3] = fmaf(a.x, b.w, p[0][3]);
    p[1][0] = fmaf(a.y, b.x, p[1][0]);
    p[1][1] = fmaf(a.y, b.y, p[1][1]);
    p[1][2] = fmaf(a.y, b.z, p[1][2]);
    p[1][3] = fmaf(a.y, b.w, p[1][3]);
    p[2][0] = fmaf(a.z, b.x, p[2][0]);
    p[2][1] = fmaf(a.z, b.y, p[2][1]);
    p[2][2] = fmaf(a.z, b.z, p[2][2]);
    p[2][3] = fmaf(a.z, b.w, p[2][3]);
    p[3][0] = fmaf(a.w, b.x, p[3][0]);
    p[3][1] = fmaf(a.w, b.y, p[3][1]);
    p[3][2] = fmaf(a.w, b.z, p[3][2]);
    p[3][3] = fmaf(a.w, b.w, p[3][3]);
  }
}

__device__ __forceinline__ void storeTile(float* dst, int rt, int ct,
                                          const float p[4][4]) {
#pragma unroll
  for (int i = 0; i < 4; ++i)
    *reinterpret_cast<float4*>(dst + (rt * 4 + i) * NMAT + ct * 4) =
        make_float4(p[i][0], p[i][1], p[i][2], p[i][3]);
}

__device__ __forceinline__ void loadMat(float* dst,
                                        const float* __restrict__ src,
                                        int tid) {
#pragma unroll
  for (int j = 0; j < 4; ++j)
    *reinterpret_cast<float4*>(dst + j * 1024 + tid * 4) =
        *reinterpret_cast<const float4*>(src + j * 1024 + tid * 4);
}

__device__ __forceinline__ float4 id4(int base) {
  return make_float4(((base + 0) % 65) == 0 ? 1.f : 0.f,
                     ((base + 1) % 65) == 0 ? 1.f : 0.f,
                     ((base + 2) % 65) == 0 ? 1.f : 0.f,
                     ((base + 3) % 65) == 0 ? 1.f : 0.f);
}

__device__ float block_ns(const float* lA, float* lY, float* lZ, float* lW,
                          float* red, int iters) {
  const int tid = threadIdx.x;
  const int rt = tid >> 4, ct = tid & 15;
  float ss = 0.0f;
#pragma unroll
  for (int j = 0; j < 4; ++j) {
    float4 v = *reinterpret_cast<const float4*>(lA + j * 1024 + tid * 4);
    ss += v.x * v.x + v.y * v.y + v.z * v.z + v.w * v.w;
  }
  red[tid] = ss;
  __syncthreads();
  for (int off = 128; off > 0; off >>= 1) {
    if (tid < off) red[tid] += red[tid + off];
    __syncthreads();
  }
  const float c = sqrtf(red[0] * 0.5f);
  const float rc = 1.0f / c;
#pragma unroll
  for (int j = 0; j < 4; ++j) {
    int base = j * 1024 + tid * 4;
    float4 v = *reinterpret_cast<const float4*>(lA + base);
    v.x *= rc;
    v.y *= rc;
    v.z *= rc;
    v.w *= rc;
    *reinterpret_cast<float4*>(lY + base) = v;
    *reinterpret_cast<float4*>(lZ + base) = id4(base);
  }
  __syncthreads();
  for (int it = 0; it < iters; ++it) {
    float p[4][4];
    mm64T(lZ, lY, rt, ct, p);
    float w[4][4];
#pragma unroll
    for (int i = 0; i < 4; ++i)
#pragma unroll
      for (int j = 0; j < 4; ++j)
        w[i][j] = ((rt * 4 + i) == (ct * 4 + j) ? 1.5f : 0.0f) - 0.5f * p[i][j];
    storeTile(lW, rt, ct, w);
    __syncthreads();
    float py[4][4], pz[4][4];
    mm64T(lY, lW, rt, ct, py);
    mm64T(lW, lZ, rt, ct, pz);
    __syncthreads();
    storeTile(lY, rt, ct, py);
    storeTile(lZ, rt, ct, pz);
    __syncthreads();
  }
  return c;
}

// K1: blocks [0,NBLK_RED) partial-sum x into `pg` (out scratch); block
// NBLK_RED does Bs = bias^{1/2}.
__global__ __launch_bounds__(256) void k1_mean_bias(
    const float* __restrict__ x, const float* __restrict__ bias,
    float* __restrict__ ws, float* __restrict__ pg) {
  const int tid = threadIdx.x;
  if (blockIdx.x < NBLK_RED) {
    float acc[16];
#pragma unroll
    for (int j = 0; j < 16; ++j) acc[j] = 0.f;
    for (int i = blockIdx.x; i < BATCH; i += NBLK_RED) {
      const float* src = x + (size_t)i * MSIZE;
#pragma unroll
      for (int j = 0; j < 4; ++j) {
        float4 v = *reinterpret_cast<const float4*>(src + j * 1024 + tid * 4);
        acc[j * 4 + 0] += v.x;
        acc[j * 4 + 1] += v.y;
        acc[j * 4 + 2] += v.z;
        acc[j * 4 + 3] += v.w;
      }
    }
    float* dst = pg + (size_t)blockIdx.x * MSIZE;
#pragma unroll
    for (int j = 0; j < 4; ++j)
      *reinterpret_cast<float4*>(dst + j * 1024 + tid * 4) = make_float4(
          acc[j * 4 + 0], acc[j * 4 + 1], acc[j * 4 + 2], acc[j * 4 + 3]);
  } else {
    __shared__ __align__(16) float lA[MSIZE], lY[MSIZE], lZ[MSIZE], lW[MSIZE];
    __shared__ float red[257];
    loadMat(lA, bias, tid);
    __syncthreads();
    float c = block_ns(lA, lY, lZ, lW, red, NS_ITERS_BIAS);
    float sc = sqrtf(c);
#pragma unroll
    for (int j = 0; j < 4; ++j) {
      int base = j * 1024 + tid * 4;
      float4 v = *reinterpret_cast<const float4*>(lY + base);
      v.x *= sc;
      v.y *= sc;
      v.z *= sc;
      v.w *= sc;
      *reinterpret_cast<float4*>(ws + BS_OFF + base) = v;
    }
  }
}

// Two-stage partial reduce. grid = (4, NY): block (bx, by) sums parts
// p = by, by+NY, ... for its 1 KB element range; writes slot `by` of dst.
__global__ __launch_bounds__(256) void k_reduce_parts(
    const float* __restrict__ src, float* __restrict__ dst, int nparts,
    float scale) {
  int e4 = blockIdx.x * 256 + threadIdx.x;
  float4 acc = make_float4(0.f, 0.f, 0.f, 0.f);
  for (int b = blockIdx.y; b < nparts; b += gridDim.y) {
    float4 v =
        *reinterpret_cast<const float4*>(src + (size_t)b * MSIZE + e4 * 4);
    acc.x += v.x;
    acc.y += v.y;
    acc.z += v.z;
    acc.w += v.w;
  }
  acc.x *= scale;
  acc.y *= scale;
  acc.z *= scale;
  acc.w *= scale;
  *reinterpret_cast<float4*>(dst + (size_t)blockIdx.y * MSIZE + e4 * 4) = acc;
}

__global__ __launch_bounds__(256) void k2_mean_ns(float* __restrict__ ws) {
  __shared__ __align__(16) float lA[MSIZE], lY[MSIZE], lZ[MSIZE], lW[MSIZE];
  __shared__ float red[257];
  const int tid = threadIdx.x;
  loadMat(lA, ws + G_OFF, tid);
  __syncthreads();
  float c = block_ns(lA, lY, lZ, lW, red, NS_ITERS_MEAN);
  float sc = sqrtf(c), rs = 1.0f / sqrtf(c);
#pragma unroll
  for (int j = 0; j < 4; ++j) {
    int base = j * 1024 + tid * 4;
    float4 y = *reinterpret_cast<const float4*>(lY + base);
    float4 z = *reinterpret_cast<const float4*>(lZ + base);
    *reinterpret_cast<float4*>(ws + GS_OFF + base) =
        make_float4(y.x * sc, y.y * sc, y.z * sc, y.w * sc);
    *reinterpret_cast<float4*>(ws + GIS_OFF + base) =
        make_float4(z.x * rs, z.y * rs, z.z * rs, z.w * rs);
  }
}

// ============================ K3: MFMA Chebyshev log-sum ====================
// 768 threads = 3 independent 4-wave chains; grid 256 (1 block/CU, 12 waves).
// 4 LDS arrays/chain: A0/A1 = X then U (hi/lo, resident through recurrence);
// A2/A3 = P0 (hi/lo) then T ping-pong (A2 even, A3 odd, bf16-only).
// U's A-op fragments re-read from LDS each step (no uh/ul register cache):
// live arch VGPRs ~58 < 64 -> no scratch spills even at the 64-arch split
// the backend forces for MFMA kernels.
__global__ __attribute__((amdgpu_flat_work_group_size(768, 768),
                          amdgpu_waves_per_eu(3, 3))) void
k3_logsum_mfma(const float* __restrict__ x, const float* __restrict__ ws,
               float* __restrict__ pm) {
  __shared__ __align__(16) short GisH[GSTR * 8], GisL[GSTR * 8];
  __shared__ __align__(16) short SH[K3_CHAINS][4][GSTR * 8];
  const int tid = threadIdx.x;
  const int ch = tid >> 8;   // chain 0..2
  const int ct = tid & 255;  // thread within chain
  const int w4 = ct >> 6;    // wave within chain
  const int R = w4 >> 1, Cb = w4 & 1;
  const int lane = tid & 63;
  const int ln = lane & 31, q = lane >> 5;
  const int col = 32 * Cb + ln;
  short* A0 = SH[ch][0];
  short* A1 = SH[ch][1];
  short* A2 = SH[ch][2];
  short* A3 = SH[ch][3];

  const float m = 0.5f * (CHEB_LO + CHEB_HI), hh = 0.5f * (CHEB_HI - CHEB_LO);
  const float invh = 1.0f / hh;
  const float beta = hh / m;
  const float zeta = (1.0f - sqrtf(1.0f - beta * beta)) / beta;
  const float ca0 = logf(m) - log1pf(zeta * zeta);
  const float ca1 = 2.0f * zeta;

  // diagonal index: r_dg = r for which row(r)==col (or -1). row(r) =
  // 32R + (r&3) + 8(r>>2) + 4q.
  int d = col - 32 * R - 4 * q;
  const int r_dg =
      (d >= 0 && d < 32 && (d & 4) == 0) ? ((d >> 3) * 4 + (d & 3)) : -1;

  if (ch == 0) stageT(ws + GIS_OFF, GisH, GisL, ct);
  __syncthreads();

  float Mac[16];
#pragma unroll
  for (int r = 0; r < 16; ++r) Mac[r] = 0.0f;

  const int g = blockIdx.x * K3_CHAINS + ch;  // global chain id, [0,768)
  for (int mat = g; mat < BATCH; mat += NBLK_K3 * K3_CHAINS) {
    stageT(x + (size_t)mat * MSIZE, A0, A1, ct);
    __syncthreads();  // b1: X visible
    // mm1: P0 = X * Gis  (A = X frags from A0/A1, B = Gis shared) -> A2/A3
    floatx16 acc;
#pragma unroll
    for (int r = 0; r < 16; ++r) acc[r] = 0.0f;
#pragma unroll
    for (int kb = 0; kb < 4; ++kb) {
      bf16x8 axh = readFrag(A0, kb, q, 32 * R + ln);
      bf16x8 axl = readFrag(A1, kb, q, 32 * R + ln);
      bf16x8 gbh = readFrag(GisH, kb, q, col);
      bf16x8 gbl = readFrag(GisL, kb, q, col);
      acc = MFMA(axl, gbh, acc);
      acc = MFMA(axh, gbl, acc);
      acc = MFMA(axh, gbh, acc);
    }
    float tmp[16];
#pragma unroll
    for (int r = 0; r < 16; ++r) tmp[r] = acc[r];
    storeChl(A2, A3, tmp, R, col, q);  // P0 -> A2/A3 (X untouched)
    __syncthreads();  // b2: P0 visible; all X reads done
    // mm2: S = Gis * P0 -> U = (S - mI)/h; U -> A0/A1 (X dead)
#pragma unroll
    for (int r = 0; r < 16; ++r) acc[r] = 0.0f;
#pragma unroll
    for (int kb = 0; kb < 4; ++kb) {
      bf16x8 gah = readFrag(GisH, kb, q, 32 * R + ln);
      bf16x8 gal = readFrag(GisL, kb, q, 32 * R + ln);
      bf16x8 bph = readFrag(A2, kb, q, col);
      bf16x8 bpl = readFrag(A3, kb, q, col);
      acc = MFMA(gal, bph, acc);
      acc = MFMA(gah, bpl, acc);
      acc = MFMA(gah, bph, acc);
    }
    float pOdd[16], pEven[16];
#pragma unroll
    for (int r = 0; r < 16; ++r) {
      float dgr = (r == r_dg) ? 1.0f : 0.0f;
      pOdd[r] = (acc[r] - m * dgr) * invh;
      Mac[r] += ca0 * dgr + ca1 * pOdd[r];
    }
    storeChl(A0, A1, pOdd, R, col, q);  // U -> A0/A1
    __syncthreads();  // b3: U visible; all P0 reads done
    // k = 2: T2 = 2 U*U - I (A-op U re-read hi/lo, B-op U hi/lo)
#pragma unroll
    for (int r = 0; r < 16; ++r) acc[r] = 0.0f;
#pragma unroll
    for (int kb = 0; kb < 4; ++kb) {
      bf16x8 auh = readFrag(A0, kb, q, 32 * R + ln);
      bf16x8 aul = readFrag(A1, kb, q, 32 * R + ln);
      bf16x8 buh = readFrag(A0, kb, q, col);
      bf16x8 bul = readFrag(A1, kb, q, col);
      acc = MFMA(aul, buh, acc);
      acc = MFMA(auh, bul, acc);
      acc = MFMA(auh, buh, acc);
    }
    float zk = zeta * zeta;
#pragma unroll
    for (int r = 0; r < 16; ++r) {
      float dgr = (r == r_dg) ? 1.0f : 0.0f;
      pEven[r] = 2.0f * acc[r] - dgr;
      Mac[r] += -zk * pEven[r];  // ak(k=2) = -2*zk/2
    }
    storeChi(A2, pEven, R, col, q);  // T2 -> A2 (P0-hi dead)
    __syncthreads();  // b4: T2 visible
    // k = 3..DEG in pairs: odd k reads T(A2), stores A3; even k reads T(A3),
    // stores A2. A-op U re-read from A0/A1 each step. In-place pOdd/pEven.
    for (int kk = 3; kk < DEG; kk += 2) {
      // odd step k = kk
#pragma unroll
      for (int r = 0; r < 16; ++r) acc[r] = 0.0f;
#pragma unroll
      for (int kb = 0; kb < 4; ++kb) {
        bf16x8 auh = readFrag(A0, kb, q, 32 * R + ln);
        bf16x8 aul = readFrag(A1, kb, q, 32 * R + ln);
        bf16x8 b = readFrag(A2, kb, q, col);
        acc = MFMA(aul, b, acc);
        acc = MFMA(auh, b, acc);
      }
      zk *= -zeta;
      {
        float ak = -2.0f * zk / (float)kk;
#pragma unroll
        for (int r = 0; r < 16; ++r) {
          pOdd[r] = 2.0f * acc[r] - pOdd[r];
          Mac[r] += ak * pOdd[r];
        }
      }
      storeChi(A3, pOdd, R, col, q);  // kk <= DEG-1, always needed
      __syncthreads();
      // even step k = kk+1
#pragma unroll
      for (int r = 0; r < 16; ++r) acc[r] = 0.0f;
#pragma unroll
      for (int kb = 0; kb < 4; ++kb) {
        bf16x8 auh = readFrag(A0, kb, q, 32 * R + ln);
        bf16x8 aul = readFrag(A1, kb, q, 32 * R + ln);
        bf16x8 b = readFrag(A3, kb, q, col);
        acc = MFMA(aul, b, acc);
        acc = MFMA(auh, b, acc);
      }
      zk *= -zeta;
      {
        float ak = -2.0f * zk / (float)(kk + 1);
#pragma unroll
        for (int r = 0; r < 16; ++r) {
          pEven[r] = 2.0f * acc[r] - pEven[r];
          Mac[r] += ak * pEven[r];
        }
      }
      if (kk + 1 < DEG) storeChi(A2, pEven, R, col, q);
      __syncthreads();
    }
  }
  // per-chain partial (768 total)
  float* dst = pm + (size_t)g * MSIZE;
#pragma unroll
  for (int r = 0; r < 16; ++r) {
    int row = 32 * R + (r & 3) + 8 * (r >> 2) + 4 * q;
    dst[row * 64 + col] = Mac[r];
  }
}

// K4: E = expm(Mbar); G1 = Gs E Gs; Gis1 = sym(G1)^{-1/2}; C = Bs Gis1 -> ws.
__global__ __launch_bounds__(256) void k4_center(float* __restrict__ ws) {
  __shared__ __align__(16) float lA[MSIZE], lY[MSIZE], lZ[MSIZE], lW[MSIZE];
  __shared__ float red[257];
  const int tid = threadIdx.x;
  const int rt = tid >> 4, ct = tid & 15;
  loadMat(lA, ws + MBAR_OFF, tid);
  __syncthreads();
  if (tid == 0) {
    float mu = 0.f;
    for (int i = 0; i < NMAT; ++i) mu += lA[i * 65];
    red[256] = mu * (1.0f / NMAT);
  }
  __syncthreads();
  const float mu = red[256];
  float ss = 0.f;
#pragma unroll
  for (int j = 0; j < 4; ++j) {
    int base = j * 1024 + tid * 4;
    float4 v = *reinterpret_cast<const float4*>(lA + base);
    float4 idm = id4(base);
    v.x -= mu * idm.x;
    v.y -= mu * idm.y;
    v.z -= mu * idm.z;
    v.w -= mu * idm.w;
    ss += v.x * v.x + v.y * v.y + v.z * v.z + v.w * v.w;
    *reinterpret_cast<float4*>(lA + base) = v;
  }
  red[tid] = ss;
  __syncthreads();
  for (int off = 128; off > 0; off >>= 1) {
    if (tid < off) red[tid] += red[tid + off];
    __syncthreads();
  }
  float nrm = sqrtf(red[0]);
  int s = 0;
  while (nrm > 0.25f && s < 12) {
    nrm *= 0.5f;
    s++;
  }
  const float dscale = exp2f((float)-s);
#pragma unroll
  for (int j = 0; j < 4; ++j) {
    int base = j * 1024 + tid * 4;
    float4 v = *reinterpret_cast<const float4*>(lA + base);
    v.x *= dscale;
    v.y *= dscale;
    v.z *= dscale;
    v.w *= dscale;
    *reinterpret_cast<float4*>(lA + base) = v;
    float4 idm = id4(base);
    *reinterpret_cast<float4*>(lY + base) =
        make_float4(idm.x + v.x * 0.125f, idm.y + v.y * 0.125f,
                    idm.z + v.z * 0.125f, idm.w + v.w * 0.125f);
  }
  __syncthreads();
  float p[4][4];
  for (int j = 7; j >= 1; --j) {
    mm64T(lA, lY, rt, ct, p);
    __syncthreads();
    float w[4][4];
    const float rj = 1.0f / (float)j;
#pragma unroll
    for (int i = 0; i < 4; ++i)
#pragma unroll
      for (int jj = 0; jj < 4; ++jj)
        w[i][jj] =
            p[i][jj] * rj + (((rt * 4 + i) == (ct * 4 + jj)) ? 1.0f : 0.0f);
    storeTile(lY, rt, ct, w);
    __syncthreads();
  }
  for (int tq = 0; tq < s; ++tq) {
    mm64T(lY, lY, rt, ct, p);
    __syncthreads();
    storeTile(lY, rt, ct, p);
    __syncthreads();
  }
  const float emu = expf(mu);
#pragma unroll
  for (int j = 0; j < 4; ++j) {
    int base = j * 1024 + tid * 4;
    float4 v = *reinterpret_cast<const float4*>(lY + base);
    v.x *= emu;
    v.y *= emu;
    v.z *= emu;
    v.w *= emu;
    *reinterpret_cast<float4*>(lY + base) = v;
  }
  __syncthreads();
  loadMat(lZ, ws + GS_OFF, tid);
  __syncthreads();
  mm64T(lY, lZ, rt, ct, p);  // E Gs
  __syncthreads();
  storeTile(lW, rt, ct, p);
  __syncthreads();
  mm64T(lZ, lW, rt, ct, p);  // G1 = Gs E Gs
  __syncthreads();
  storeTile(lA, rt, ct, p);
  __syncthreads();
  float qq[4][4];
#pragma unroll
  for (int i = 0; i < 4; ++i)
#pragma unroll
    for (int j = 0; j < 4; ++j)
      qq[i][j] = 0.5f * (p[i][j] + lA[(ct * 4 + j) * NMAT + rt * 4 + i]);
  __syncthreads();
  storeTile(lA, rt, ct, qq);
  __syncthreads();
  float c = block_ns(lA, lY, lZ, lW, red, NS_ITERS_MEAN);
  const float rs = 1.0f / sqrtf(c);
#pragma unroll
  for (int j = 0; j < 4; ++j) {  // Gis1 -> lY
    int base = j * 1024 + tid * 4;
    float4 v = *reinterpret_cast<const float4*>(lZ + base);
    *reinterpret_cast<float4*>(lY + base) =
        make_float4(v.x * rs, v.y * rs, v.z * rs, v.w * rs);
  }
  __syncthreads();
  loadMat(lZ, ws + BS_OFF, tid);
  __syncthreads();
  mm64T(lZ, lY, rt, ct, p);  // C = Bs Gis1
#pragma unroll
  for (int i = 0; i < 4; ++i)
#pragma unroll
    for (int j = 0; j < 4; ++j)
      ws[C_OFF + (rt * 4 + i) * NMAT + ct * 4 + j] = p[i][j];
}

// ============================ K5: out = C X C^T (MFMA) ======================
// 1024 threads = 4 chains, grid 256 (1 block/CU, 16 waves), explicit amdgpu
// attributes. C^T staged once per block into a shared LDS pair. 2 LDS arrays
// per chain: X then P' time-share (A0,A1) with one extra barrier.
// mm1: P' = X*C^T (A = X frags, B = C^T frags); mm2: O = C*P'.
__global__ __attribute__((amdgpu_flat_work_group_size(1024, 1024),
                          amdgpu_waves_per_eu(4, 4))) void
k5_out_mfma(const float* __restrict__ x, const float* __restrict__ ws,
            float* __restrict__ out) {
  __shared__ __align__(16) short CtH[GSTR * 8], CtL[GSTR * 8];
  __shared__ __align__(16) short SH[K5_CHAINS][2][GSTR * 8];
  const int tid = threadIdx.x;
  const int ch = tid >> 8;
  const int ct = tid & 255;
  const int w4 = ct >> 6;
  const int R = w4 >> 1, Cb = w4 & 1;
  const int lane = tid & 63;
  const int ln = lane & 31, q = lane >> 5;
  const int col = 32 * Cb + ln;
  short* A0 = SH[ch][0];
  short* A1 = SH[ch][1];

  if (ch == 0) stageT(ws + C_OFF, CtH, CtL, ct);  // arr(k,n) = C[n][k]
  __syncthreads();

  for (int it = 0; it < CHAIN_MATS; ++it) {
    const int mat = blockIdx.x * (K5_CHAINS * CHAIN_MATS) + ch * CHAIN_MATS + it;
    stageT(x + (size_t)mat * MSIZE, A0, A1, ct);
    __syncthreads();
    floatx16 acc;
#pragma unroll
    for (int r = 0; r < 16; ++r) acc[r] = 0.0f;
#pragma unroll
    for (int kb = 0; kb < 4; ++kb) {
      bf16x8 axh = readFrag(A0, kb, q, 32 * R + ln);
      bf16x8 axl = readFrag(A1, kb, q, 32 * R + ln);
      bf16x8 cbh = readFrag(CtH, kb, q, col);  // B-op C^T
      bf16x8 cbl = readFrag(CtL, kb, q, col);
      acc = MFMA(axl, cbh, acc);
      acc = MFMA(axh, cbl, acc);
      acc = MFMA(axh, cbh, acc);
    }
    __syncthreads();  // all waves finished reading X
    float tmp[16];
#pragma unroll
    for (int r = 0; r < 16; ++r) tmp[r] = acc[r];
    storeChl(A0, A1, tmp, R, col, q);  // P' overwrites X
    __syncthreads();
#pragma unroll
    for (int r = 0; r < 16; ++r) acc[r] = 0.0f;
#pragma unroll
    for (int kb = 0; kb < 4; ++kb) {
      bf16x8 cah = readFrag(CtH, kb, q, 32 * R + ln);  // A-op C
      bf16x8 cal = readFrag(CtL, kb, q, 32 * R + ln);
      bf16x8 bph = readFrag(A0, kb, q, col);
      bf16x8 bpl = readFrag(A1, kb, q, col);
      acc = MFMA(cal, bph, acc);
      acc = MFMA(cah, bpl, acc);
      acc = MFMA(cah, bph, acc);
    }
    float* dst = out + (size_t)mat * MSIZE;
#pragma unroll
    for (int r = 0; r < 16; ++r) {
      int row = 32 * R + (r & 3) + 8 * (r >> 2) + 4 * q;
      dst[row * 64 + col] = acc[r];
    }
    __syncthreads();
  }
}

extern "C" void kernel_launch(void* const* d_in, const int* in_sizes, int n_in,
                              void* d_out, int out_size, void* d_ws,
                              size_t ws_size, hipStream_t stream) {
  const float* x = (const float*)d_in[0];
  const float* bias = (const float*)d_in[1];
  float* out = (float*)d_out;
  float* ws = (float*)d_ws;
  const float invB = 1.0f / (float)BATCH;
  float* red1 = out + (size_t)RED1_SLOT * MSIZE;  // 64 stage-1 slots in out

  k1_mean_bias<<<NBLK_RED + 1, 256, 0, stream>>>(x, bias, ws, out);
  k_reduce_parts<<<dim3(4, 32), 256, 0, stream>>>(out, red1, NBLK_RED, 1.0f);
  k_reduce_parts<<<dim3(4, 1), 256, 0, stream>>>(red1, ws + G_OFF, 32, invB);
  k2_mean_ns<<<1, 256, 0, stream>>>(ws);
  k3_logsum_mfma<<<NBLK_K3, 768, 0, stream>>>(x, ws, out);
  k_reduce_parts<<<dim3(4, 64), 256, 0, stream>>>(out, red1,
                                                  NBLK_K3 * K3_CHAINS, 1.0f);
  k_reduce_parts<<<dim3(4, 1), 256, 0, stream>>>(red1, ws + MBAR_OFF, 64, invB);
  k4_center<<<1, 256, 0, stream>>>(ws);
  k5_out_mfma<<<NBLK_K5, 1024, 0, stream>>>(x, ws, out);
}

// Round 9
// 551.902 us; speedup vs baseline: 1.4482x; 1.2855x over previous
//
#include <hip/hip_runtime.h>

// ---------------------------------------------------------------------------
// SPDBatchNormMean forward, B=8192, n=64, fp32. Eigendecomp-free:
//   G0 = mean(x); Gs/Gis = G0^{±1/2} (Newton-Schulz); M = mean log(Gis x Gis)
//   (deg-18 Chebyshev on [0.3,4.0]); G1 = Gs expm(M) Gs; Gis1 = G1^{-1/2};
//   C = Bs Gis1 (Bs = bias^{1/2}); out = C x C^T.
// Round 11: MFMA-ize the single-block kernels. Round-10 fixed k3 (211us,
// VGPR 84, no spills); accounting shows ~300us of the remaining ~500 is
// k1-bias/k2/k4 running 64^3 matmuls on the VALU of ONE CU (~5K cyc each).
// All their matrices are symmetric (polynomials of symmetric inputs), so the
// k3-proven hi/lo bf16 MFMA machinery applies directly:
//   - splitT: fp32 LDS/global matrix -> transposed hi/lo split (A-op layout;
//     == B-op layout for symmetric matrices). splitI: identity split.
//   - mm3: 12-MFMA hi/lo 3-term 64^3 matmul per 4-wave group.
//   - block_ns_mfma: NS iteration (W=1.5I-0.5ZY; Y<-YW; Z<-WZ) on MFMA,
//     state carried as hi/lo splits (same effective precision as the bf16
//     splits k3/k5 already apply to Gis/C).
//   - k4: Horner/squaring/E*Gs/Gs*W'/Bs*Gis1 all on MFMA; only mu/norm/
//     symmetrize passes remain VALU. Non-symmetric W'=E*Gs handled via
//     direct C/D->B-layout store (k3's P0 path).
// k3/k5 unchanged from round 10.
// ---------------------------------------------------------------------------

#define BATCH 8192
#define NMAT 64
#define MSIZE 4096
#define NBLK_RED 512
#define NBLK_K3 256
#define K3_CHAINS 3
#define K5_CHAINS 4
#define CHAIN_MATS 8
#define NBLK_K5 256
#define DEG 18
#define CHEB_LO 0.30f
#define CHEB_HI 4.00f
#define NS_ITERS_MEAN 10
#define NS_ITERS_BIAS 12
#define GSTR 520 /* padded k-group stride (65*8 elems, 16B-aligned) */

// workspace layout (floats): only the 6 small matrices (96 KB).
#define G_OFF 0
#define BS_OFF (G_OFF + MSIZE)
#define GS_OFF (BS_OFF + MSIZE)
#define GIS_OFF (GS_OFF + MSIZE)
#define MBAR_OFF (GIS_OFF + MSIZE)
#define C_OFF (MBAR_OFF + MSIZE)
// scratch staged in `out` (128 MB, dead until k5): partial slots [0,768),
// stage-1 reduce slots at [RED1_SLOT, RED1_SLOT+64).
#define RED1_SLOT 2048

typedef __attribute__((ext_vector_type(8))) short bf16x8;
typedef __attribute__((ext_vector_type(16))) float floatx16;
#define MFMA(a, b, c) __builtin_amdgcn_mfma_f32_32x32x16_bf16(a, b, c, 0, 0, 0)

__device__ __forceinline__ short f2bf(float x) {
  union {
    __bf16 b;
    short s;
  } u;
  u.b = (__bf16)x;  // hardware cvt, RNE
  return u.s;
}
__device__ __forceinline__ float bf2f(short h) {
  return __uint_as_float(((unsigned)(unsigned short)h) << 16);
}

// Stage a row-major 64x64 fp32 matrix M into hi/lo bf16 arrays in B-layout
// holding M^T: arr(k,n) = M[n][k]. 256 threads (st), packed b64.
__device__ __forceinline__ void stageT(const float* __restrict__ src, short* ah,
                                       short* al, int st) {
#pragma unroll
  for (int jb = 0; jb < 4; ++jb) {
    int flat = jb * 1024 + st * 4;
    float4 v = *reinterpret_cast<const float4*>(src + flat);
    int i = flat >> 6;   // row of M
    int j0 = flat & 63;  // col base (multiple of 4)
    int addr = (j0 >> 3) * GSTR + i * 8 + (j0 & 7);
    short4 h, l;
    h.x = f2bf(v.x); l.x = f2bf(v.x - bf2f(h.x));
    h.y = f2bf(v.y); l.y = f2bf(v.y - bf2f(h.y));
    h.z = f2bf(v.z); l.z = f2bf(v.z - bf2f(h.z));
    h.w = f2bf(v.w); l.w = f2bf(v.w - bf2f(h.w));
    *reinterpret_cast<short4*>(ah + addr) = h;
    *reinterpret_cast<short4*>(al + addr) = l;
  }
}

// stageT with a scale factor (src may be LDS or global).
__device__ __forceinline__ void splitT(const float* __restrict__ src, short* ah,
                                       short* al, int st, float scale) {
#pragma unroll
  for (int jb = 0; jb < 4; ++jb) {
    int flat = jb * 1024 + st * 4;
    float4 v = *reinterpret_cast<const float4*>(src + flat);
    v.x *= scale;
    v.y *= scale;
    v.z *= scale;
    v.w *= scale;
    int i = flat >> 6;
    int j0 = flat & 63;
    int addr = (j0 >> 3) * GSTR + i * 8 + (j0 & 7);
    short4 h, l;
    h.x = f2bf(v.x); l.x = f2bf(v.x - bf2f(h.x));
    h.y = f2bf(v.y); l.y = f2bf(v.y - bf2f(h.y));
    h.z = f2bf(v.z); l.z = f2bf(v.z - bf2f(h.z));
    h.w = f2bf(v.w); l.w = f2bf(v.w - bf2f(h.w));
    *reinterpret_cast<short4*>(ah + addr) = h;
    *reinterpret_cast<short4*>(al + addr) = l;
  }
}

// Identity split: arr(k,n) = (k==n). bf16(1.0) = 0x3F80 exact.
__device__ __forceinline__ void splitI(short* ah, short* al, int st) {
#pragma unroll
  for (int jb = 0; jb < 4; ++jb) {
    int flat = jb * 1024 + st * 4;
    int i = flat >> 6;
    int j0 = flat & 63;
    int addr = (j0 >> 3) * GSTR + i * 8 + (j0 & 7);
    short4 h, l;
    h.x = (j0 + 0 == i) ? (short)0x3F80 : (short)0;
    h.y = (j0 + 1 == i) ? (short)0x3F80 : (short)0;
    h.z = (j0 + 2 == i) ? (short)0x3F80 : (short)0;
    h.w = (j0 + 3 == i) ? (short)0x3F80 : (short)0;
    l.x = 0; l.y = 0; l.z = 0; l.w = 0;
    *reinterpret_cast<short4*>(ah + addr) = h;
    *reinterpret_cast<short4*>(al + addr) = l;
  }
}

// Reconstruct fp32 row-major matrix from a split, with scale. dst may be
// LDS or global; writes are coalesced float4. (arr(k=j,n=i) read back at
// (i,j) gives M[i][j] for splitT-produced arrays; M^T for storeChl-produced
// ones — identical for the symmetric matrices this is used on.)
__device__ __forceinline__ void unsplitT(float* dst, const short* ah,
                                         const short* al, int st,
                                         float scale) {
#pragma unroll
  for (int jb = 0; jb < 4; ++jb) {
    int flat = jb * 1024 + st * 4;
    int i = flat >> 6;
    int j0 = flat & 63;
    int addr = (j0 >> 3) * GSTR + i * 8 + (j0 & 7);
    short4 h = *reinterpret_cast<const short4*>(ah + addr);
    short4 l = *reinterpret_cast<const short4*>(al + addr);
    float4 v = make_float4((bf2f(h.x) + bf2f(l.x)) * scale,
                           (bf2f(h.y) + bf2f(l.y)) * scale,
                           (bf2f(h.z) + bf2f(l.z)) * scale,
                           (bf2f(h.w) + bf2f(l.w)) * scale);
    *reinterpret_cast<float4*>(dst + flat) = v;
  }
}

// Fragment read: returns elements j=0..7 at k = kb*16 + q*8 + j, column n.
__device__ __forceinline__ bf16x8 readFrag(const short* a, int kb, int q,
                                           int n) {
  return *reinterpret_cast<const bf16x8*>(a + (kb * 2 + q) * GSTR + n * 8);
}

// Store 16 C/D-layout fp32 regs into B-layout array(s) as bf16 (direct:
// arr(k=row, n=col) = v). Packs 4 consecutive rows per b64 write.
__device__ __forceinline__ void storeChi(short* dh, const float* v, int R,
                                         int col, int q) {
#pragma unroll
  for (int g4 = 0; g4 < 4; ++g4) {
    int addr = (4 * R + g4) * GSTR + col * 8 + 4 * q;
    short4 h;
    h.x = f2bf(v[4 * g4 + 0]);
    h.y = f2bf(v[4 * g4 + 1]);
    h.z = f2bf(v[4 * g4 + 2]);
    h.w = f2bf(v[4 * g4 + 3]);
    *reinterpret_cast<short4*>(dh + addr) = h;
  }
}
__device__ __forceinline__ void storeChl(short* dh, short* dl, const float* v,
                                         int R, int col, int q) {
#pragma unroll
  for (int g4 = 0; g4 < 4; ++g4) {
    int addr = (4 * R + g4) * GSTR + col * 8 + 4 * q;
    short4 h, l;
    float a0 = v[4 * g4 + 0], a1 = v[4 * g4 + 1];
    float a2 = v[4 * g4 + 2], a3 = v[4 * g4 + 3];
    h.x = f2bf(a0); l.x = f2bf(a0 - bf2f(h.x));
    h.y = f2bf(a1); l.y = f2bf(a1 - bf2f(h.y));
    h.z = f2bf(a2); l.z = f2bf(a2 - bf2f(h.z));
    h.w = f2bf(a3); l.w = f2bf(a3 - bf2f(h.w));
    *reinterpret_cast<short4*>(dh + addr) = h;
    *reinterpret_cast<short4*>(dl + addr) = l;
  }
}

// 64^3 matmul, hi/lo 3-term: returns C/D regs of (A-op)*(B-op).
// A-op needs arr(k,n)=A[n][k] (splitT of A, or any layout if A symmetric);
// B-op needs arr(k,n)=B[k][n] (storeChl direct, or splitT if B symmetric).
__device__ __forceinline__ floatx16 mm3(const short* Ah, const short* Al,
                                        const short* Bh, const short* Bl,
                                        int R, int ln, int q, int col) {
  floatx16 acc;
#pragma unroll
  for (int r = 0; r < 16; ++r) acc[r] = 0.0f;
#pragma unroll
  for (int kb = 0; kb < 4; ++kb) {
    bf16x8 ah = readFrag(Ah, kb, q, 32 * R + ln);
    bf16x8 al = readFrag(Al, kb, q, 32 * R + ln);
    bf16x8 bh = readFrag(Bh, kb, q, col);
    bf16x8 bl = readFrag(Bl, kb, q, col);
    acc = MFMA(al, bh, acc);
    acc = MFMA(ah, bl, acc);
    acc = MFMA(ah, bh, acc);
  }
  return acc;
}

__device__ __forceinline__ void loadMat(float* dst,
                                        const float* __restrict__ src,
                                        int tid) {
#pragma unroll
  for (int j = 0; j < 4; ++j)
    *reinterpret_cast<float4*>(dst + j * 1024 + tid * 4) =
        *reinterpret_cast<const float4*>(src + j * 1024 + tid * 4);
}

__device__ __forceinline__ float4 id4(int base) {
  return make_float4(((base + 0) % 65) == 0 ? 1.f : 0.f,
                     ((base + 1) % 65) == 0 ? 1.f : 0.f,
                     ((base + 2) % 65) == 0 ? 1.f : 0.f,
                     ((base + 3) % 65) == 0 ? 1.f : 0.f);
}

// MFMA Newton-Schulz: A (fp32 LDS) -> Y ~ (A/c)^{1/2}, Z ~ (A/c)^{-1/2} as
// hi/lo splits. 256 threads. Returns c = ||A||_F/sqrt(2).
__device__ float block_ns_mfma(const float* lA, short* Yh, short* Yl, short* Zh,
                               short* Zl, short* Wh, short* Wl, float* red,
                               int iters) {
  const int tid = threadIdx.x;
  const int w4 = tid >> 6;
  const int R = w4 >> 1, Cb = w4 & 1;
  const int lane = tid & 63;
  const int ln = lane & 31, q = lane >> 5;
  const int col = 32 * Cb + ln;
  int d = col - 32 * R - 4 * q;
  const int r_dg =
      (d >= 0 && d < 32 && (d & 4) == 0) ? ((d >> 3) * 4 + (d & 3)) : -1;

  float ss = 0.0f;
#pragma unroll
  for (int j = 0; j < 4; ++j) {
    float4 v = *reinterpret_cast<const float4*>(lA + j * 1024 + tid * 4);
    ss += v.x * v.x + v.y * v.y + v.z * v.z + v.w * v.w;
  }
  red[tid] = ss;
  __syncthreads();
  for (int off = 128; off > 0; off >>= 1) {
    if (tid < off) red[tid] += red[tid + off];
    __syncthreads();
  }
  const float c = sqrtf(red[0] * 0.5f);
  const float rc = 1.0f / c;
  splitT(lA, Yh, Yl, tid, rc);  // Y0 = A/c
  splitI(Zh, Zl, tid);          // Z0 = I
  __syncthreads();
  for (int it = 0; it < iters; ++it) {
    // W = 1.5 I - 0.5 Z*Y
    floatx16 p = mm3(Zh, Zl, Yh, Yl, R, ln, q, col);
    float w[16];
#pragma unroll
    for (int r = 0; r < 16; ++r)
      w[r] = ((r == r_dg) ? 1.5f : 0.0f) - 0.5f * p[r];
    storeChl(Wh, Wl, w, R, col, q);
    __syncthreads();  // W visible (Z/Y reads already done per-wave)
    floatx16 py = mm3(Yh, Yl, Wh, Wl, R, ln, q, col);  // Ynew = Y*W
    floatx16 pz = mm3(Wh, Wl, Zh, Zl, R, ln, q, col);  // Znew = W*Z
    __syncthreads();  // all waves done reading Y,Z
    float ty[16], tz[16];
#pragma unroll
    for (int r = 0; r < 16; ++r) {
      ty[r] = py[r];
      tz[r] = pz[r];
    }
    storeChl(Yh, Yl, ty, R, col, q);
    storeChl(Zh, Zl, tz, R, col, q);
    __syncthreads();
  }
  return c;
}

// K1: blocks [0,NBLK_RED) partial-sum x into `pg` (out scratch); block
// NBLK_RED does Bs = bias^{1/2} via MFMA NS.
__global__ __launch_bounds__(256) void k1_mean_bias(
    const float* __restrict__ x, const float* __restrict__ bias,
    float* __restrict__ ws, float* __restrict__ pg) {
  const int tid = threadIdx.x;
  if (blockIdx.x < NBLK_RED) {
    float acc[16];
#pragma unroll
    for (int j = 0; j < 16; ++j) acc[j] = 0.f;
    for (int i = blockIdx.x; i < BATCH; i += NBLK_RED) {
      const float* src = x + (size_t)i * MSIZE;
#pragma unroll
      for (int j = 0; j < 4; ++j) {
        float4 v = *reinterpret_cast<const float4*>(src + j * 1024 + tid * 4);
        acc[j * 4 + 0] += v.x;
        acc[j * 4 + 1] += v.y;
        acc[j * 4 + 2] += v.z;
        acc[j * 4 + 3] += v.w;
      }
    }
    float* dst = pg + (size_t)blockIdx.x * MSIZE;
#pragma unroll
    for (int j = 0; j < 4; ++j)
      *reinterpret_cast<float4*>(dst + j * 1024 + tid * 4) = make_float4(
          acc[j * 4 + 0], acc[j * 4 + 1], acc[j * 4 + 2], acc[j * 4 + 3]);
  } else {
    __shared__ __align__(16) float lA[MSIZE];
    __shared__ float red[257];
    __shared__ __align__(16) short sY[2][GSTR * 8], sZ[2][GSTR * 8],
        sW[2][GSTR * 8];
    loadMat(lA, bias, tid);
    __syncthreads();
    float c = block_ns_mfma(lA, sY[0], sY[1], sZ[0], sZ[1], sW[0], sW[1], red,
                            NS_ITERS_BIAS);
    unsplitT(ws + BS_OFF, sY[0], sY[1], tid, sqrtf(c));
  }
}

// Two-stage partial reduce. grid = (4, NY): block (bx, by) sums parts
// p = by, by+NY, ... for its 1 KB element range; writes slot `by` of dst.
__global__ __launch_bounds__(256) void k_reduce_parts(
    const float* __restrict__ src, float* __restrict__ dst, int nparts,
    float scale) {
  int e4 = blockIdx.x * 256 + threadIdx.x;
  float4 acc = make_float4(0.f, 0.f, 0.f, 0.f);
  for (int b = blockIdx.y; b < nparts; b += gridDim.y) {
    float4 v =
        *reinterpret_cast<const float4*>(src + (size_t)b * MSIZE + e4 * 4);
    acc.x += v.x;
    acc.y += v.y;
    acc.z += v.z;
    acc.w += v.w;
  }
  acc.x *= scale;
  acc.y *= scale;
  acc.z *= scale;
  acc.w *= scale;
  *reinterpret_cast<float4*>(dst + (size_t)blockIdx.y * MSIZE + e4 * 4) = acc;
}

__global__ __launch_bounds__(256) void k2_mean_ns(float* __restrict__ ws) {
  __shared__ __align__(16) float lA[MSIZE];
  __shared__ float red[257];
  __shared__ __align__(16) short sY[2][GSTR * 8], sZ[2][GSTR * 8],
      sW[2][GSTR * 8];
  const int tid = threadIdx.x;
  loadMat(lA, ws + G_OFF, tid);
  __syncthreads();
  float c = block_ns_mfma(lA, sY[0], sY[1], sZ[0], sZ[1], sW[0], sW[1], red,
                          NS_ITERS_MEAN);
  float sc = sqrtf(c), rs = 1.0f / sqrtf(c);
  unsplitT(ws + GS_OFF, sY[0], sY[1], tid, sc);
  unsplitT(ws + GIS_OFF, sZ[0], sZ[1], tid, rs);
}

// ============================ K3: MFMA Chebyshev log-sum ====================
// 768 threads = 3 independent 4-wave chains; grid 256 (1 block/CU, 12 waves).
// 4 LDS arrays/chain: A0/A1 = X then U (hi/lo, resident through recurrence);
// A2/A3 = P0 (hi/lo) then T ping-pong. U's A-op fragments re-read from LDS
// each step (no register cache): live arch VGPRs fit the budget, no spills.
__global__ __attribute__((amdgpu_flat_work_group_size(768, 768),
                          amdgpu_waves_per_eu(3, 3))) void
k3_logsum_mfma(const float* __restrict__ x, const float* __restrict__ ws,
               float* __restrict__ pm) {
  __shared__ __align__(16) short GisH[GSTR * 8], GisL[GSTR * 8];
  __shared__ __align__(16) short SH[K3_CHAINS][4][GSTR * 8];
  const int tid = threadIdx.x;
  const int ch = tid >> 8;   // chain 0..2
  const int ct = tid & 255;  // thread within chain
  const int w4 = ct >> 6;    // wave within chain
  const int R = w4 >> 1, Cb = w4 & 1;
  const int lane = tid & 63;
  const int ln = lane & 31, q = lane >> 5;
  const int col = 32 * Cb + ln;
  short* A0 = SH[ch][0];
  short* A1 = SH[ch][1];
  short* A2 = SH[ch][2];
  short* A3 = SH[ch][3];

  const float m = 0.5f * (CHEB_LO + CHEB_HI), hh = 0.5f * (CHEB_HI - CHEB_LO);
  const float invh = 1.0f / hh;
  const float beta = hh / m;
  const float zeta = (1.0f - sqrtf(1.0f - beta * beta)) / beta;
  const float ca0 = logf(m) - log1pf(zeta * zeta);
  const float ca1 = 2.0f * zeta;

  int d = col - 32 * R - 4 * q;
  const int r_dg =
      (d >= 0 && d < 32 && (d & 4) == 0) ? ((d >> 3) * 4 + (d & 3)) : -1;

  if (ch == 0) stageT(ws + GIS_OFF, GisH, GisL, ct);
  __syncthreads();

  float Mac[16];
#pragma unroll
  for (int r = 0; r < 16; ++r) Mac[r] = 0.0f;

  const int g = blockIdx.x * K3_CHAINS + ch;  // global chain id, [0,768)
  for (int mat = g; mat < BATCH; mat += NBLK_K3 * K3_CHAINS) {
    stageT(x + (size_t)mat * MSIZE, A0, A1, ct);
    __syncthreads();  // b1: X visible
    // mm1: P0 = X * Gis  (A = X frags from A0/A1, B = Gis shared) -> A2/A3
    floatx16 acc;
#pragma unroll
    for (int r = 0; r < 16; ++r) acc[r] = 0.0f;
#pragma unroll
    for (int kb = 0; kb < 4; ++kb) {
      bf16x8 axh = readFrag(A0, kb, q, 32 * R + ln);
      bf16x8 axl = readFrag(A1, kb, q, 32 * R + ln);
      bf16x8 gbh = readFrag(GisH, kb, q, col);
      bf16x8 gbl = readFrag(GisL, kb, q, col);
      acc = MFMA(axl, gbh, acc);
      acc = MFMA(axh, gbl, acc);
      acc = MFMA(axh, gbh, acc);
    }
    float tmp[16];
#pragma unroll
    for (int r = 0; r < 16; ++r) tmp[r] = acc[r];
    storeChl(A2, A3, tmp, R, col, q);  // P0 -> A2/A3 (X untouched)
    __syncthreads();  // b2: P0 visible; all X reads done
    // mm2: S = Gis * P0 -> U = (S - mI)/h; U -> A0/A1 (X dead)
#pragma unroll
    for (int r = 0; r < 16; ++r) acc[r] = 0.0f;
#pragma unroll
    for (int kb = 0; kb < 4; ++kb) {
      bf16x8 gah = readFrag(GisH, kb, q, 32 * R + ln);
      bf16x8 gal = readFrag(GisL, kb, q, 32 * R + ln);
      bf16x8 bph = readFrag(A2, kb, q, col);
      bf16x8 bpl = readFrag(A3, kb, q, col);
      acc = MFMA(gal, bph, acc);
      acc = MFMA(gah, bpl, acc);
      acc = MFMA(gah, bph, acc);
    }
    float pOdd[16], pEven[16];
#pragma unroll
    for (int r = 0; r < 16; ++r) {
      float dgr = (r == r_dg) ? 1.0f : 0.0f;
      pOdd[r] = (acc[r] - m * dgr) * invh;
      Mac[r] += ca0 * dgr + ca1 * pOdd[r];
    }
    storeChl(A0, A1, pOdd, R, col, q);  // U -> A0/A1
    __syncthreads();  // b3: U visible; all P0 reads done
    // k = 2: T2 = 2 U*U - I
#pragma unroll
    for (int r = 0; r < 16; ++r) acc[r] = 0.0f;
#pragma unroll
    for (int kb = 0; kb < 4; ++kb) {
      bf16x8 auh = readFrag(A0, kb, q, 32 * R + ln);
      bf16x8 aul = readFrag(A1, kb, q, 32 * R + ln);
      bf16x8 buh = readFrag(A0, kb, q, col);
      bf16x8 bul = readFrag(A1, kb, q, col);
      acc = MFMA(aul, buh, acc);
      acc = MFMA(auh, bul, acc);
      acc = MFMA(auh, buh, acc);
    }
    float zk = zeta * zeta;
#pragma unroll
    for (int r = 0; r < 16; ++r) {
      float dgr = (r == r_dg) ? 1.0f : 0.0f;
      pEven[r] = 2.0f * acc[r] - dgr;
      Mac[r] += -zk * pEven[r];  // ak(k=2) = -2*zk/2
    }
    storeChi(A2, pEven, R, col, q);  // T2 -> A2 (P0-hi dead)
    __syncthreads();  // b4: T2 visible
    // k = 3..DEG in pairs: odd k reads T(A2), stores A3; even k reads T(A3),
    // stores A2. A-op U re-read from A0/A1 each step. In-place pOdd/pEven.
    for (int kk = 3; kk < DEG; kk += 2) {
#pragma unroll
      for (int r = 0; r < 16; ++r) acc[r] = 0.0f;
#pragma unroll
      for (int kb = 0; kb < 4; ++kb) {
        bf16x8 auh = readFrag(A0, kb, q, 32 * R + ln);
        bf16x8 aul = readFrag(A1, kb, q, 32 * R + ln);
        bf16x8 b = readFrag(A2, kb, q, col);
        acc = MFMA(aul, b, acc);
        acc = MFMA(auh, b, acc);
      }
      zk *= -zeta;
      {
        float ak = -2.0f * zk / (float)kk;
#pragma unroll
        for (int r = 0; r < 16; ++r) {
          pOdd[r] = 2.0f * acc[r] - pOdd[r];
          Mac[r] += ak * pOdd[r];
        }
      }
      storeChi(A3, pOdd, R, col, q);
      __syncthreads();
#pragma unroll
      for (int r = 0; r < 16; ++r) acc[r] = 0.0f;
#pragma unroll
      for (int kb = 0; kb < 4; ++kb) {
        bf16x8 auh = readFrag(A0, kb, q, 32 * R + ln);
        bf16x8 aul = readFrag(A1, kb, q, 32 * R + ln);
        bf16x8 b = readFrag(A3, kb, q, col);
        acc = MFMA(aul, b, acc);
        acc = MFMA(auh, b, acc);
      }
      zk *= -zeta;
      {
        float ak = -2.0f * zk / (float)(kk + 1);
#pragma unroll
        for (int r = 0; r < 16; ++r) {
          pEven[r] = 2.0f * acc[r] - pEven[r];
          Mac[r] += ak * pEven[r];
        }
      }
      if (kk + 1 < DEG) storeChi(A2, pEven, R, col, q);
      __syncthreads();
    }
  }
  // per-chain partial (768 total)
  float* dst = pm + (size_t)g * MSIZE;
#pragma unroll
  for (int r = 0; r < 16; ++r) {
    int row = 32 * R + (r & 3) + 8 * (r >> 2) + 4 * q;
    dst[row * 64 + col] = Mac[r];
  }
}

// K4: E = expm(Mbar); G1 = Gs E Gs; Gis1 = sym(G1)^{-1/2}; C = Bs Gis1 -> ws.
// All 64^3 matmuls on MFMA (hi/lo splits); only mu/norm/symmetrize on VALU.
__global__ __launch_bounds__(256) void k4_center(float* __restrict__ ws) {
  __shared__ __align__(16) float lA[MSIZE];
  __shared__ float red[257];
  __shared__ __align__(16) short sA[2][GSTR * 8], sY[2][GSTR * 8],
      sZ[2][GSTR * 8], sW[2][GSTR * 8];
  const int tid = threadIdx.x;
  const int w4 = tid >> 6;
  const int R = w4 >> 1, Cb = w4 & 1;
  const int lane = tid & 63;
  const int ln = lane & 31, q = lane >> 5;
  const int col = 32 * Cb + ln;
  int dd = col - 32 * R - 4 * q;
  const int r_dg =
      (dd >= 0 && dd < 32 && (dd & 4) == 0) ? ((dd >> 3) * 4 + (dd & 3)) : -1;

  loadMat(lA, ws + MBAR_OFF, tid);
  __syncthreads();
  if (tid == 0) {
    float mu = 0.f;
    for (int i = 0; i < NMAT; ++i) mu += lA[i * 65];
    red[256] = mu * (1.0f / NMAT);
  }
  __syncthreads();
  const float mu = red[256];
  float ss = 0.f;
#pragma unroll
  for (int j = 0; j < 4; ++j) {
    int base = j * 1024 + tid * 4;
    float4 v = *reinterpret_cast<const float4*>(lA + base);
    float4 idm = id4(base);
    v.x -= mu * idm.x;
    v.y -= mu * idm.y;
    v.z -= mu * idm.z;
    v.w -= mu * idm.w;
    ss += v.x * v.x + v.y * v.y + v.z * v.z + v.w * v.w;
    *reinterpret_cast<float4*>(lA + base) = v;
  }
  red[tid] = ss;
  __syncthreads();
  for (int off = 128; off > 0; off >>= 1) {
    if (tid < off) red[tid] += red[tid + off];
    __syncthreads();
  }
  float nrm = sqrtf(red[0]);
  int s = 0;
  while (nrm > 0.25f && s < 12) {
    nrm *= 0.5f;
    s++;
  }
  const float dscale = exp2f((float)-s);
  // A' = (Mbar - mu I)*dscale split; Y0 = I + A'/8 split.
  splitT(lA, sA[0], sA[1], tid, dscale);
#pragma unroll
  for (int jb = 0; jb < 4; ++jb) {
    int flat = jb * 1024 + tid * 4;
    float4 v = *reinterpret_cast<const float4*>(lA + flat);
    float4 idm = id4(flat);
    v.x = idm.x + 0.125f * dscale * v.x;
    v.y = idm.y + 0.125f * dscale * v.y;
    v.z = idm.z + 0.125f * dscale * v.z;
    v.w = idm.w + 0.125f * dscale * v.w;
    int i = flat >> 6, j0 = flat & 63;
    int addr = (j0 >> 3) * GSTR + i * 8 + (j0 & 7);
    short4 h, l;
    h.x = f2bf(v.x); l.x = f2bf(v.x - bf2f(h.x));
    h.y = f2bf(v.y); l.y = f2bf(v.y - bf2f(h.y));
    h.z = f2bf(v.z); l.z = f2bf(v.z - bf2f(h.z));
    h.w = f2bf(v.w); l.w = f2bf(v.w - bf2f(h.w));
    *reinterpret_cast<short4*>(sY[0] + addr) = h;
    *reinterpret_cast<short4*>(sY[1] + addr) = l;
  }
  __syncthreads();
  // Horner: for j=7..1: Y = (A'*Y)/j + I
  for (int j = 7; j >= 1; --j) {
    floatx16 p = mm3(sA[0], sA[1], sY[0], sY[1], R, ln, q, col);
    const float rj = 1.0f / (float)j;
    float w[16];
#pragma unroll
    for (int r = 0; r < 16; ++r)
      w[r] = p[r] * rj + ((r == r_dg) ? 1.0f : 0.0f);
    __syncthreads();  // all reads of Y done
    storeChl(sY[0], sY[1], w, R, col, q);
    __syncthreads();
  }
  // squarings: Y = Y*Y, s times
  for (int tq = 0; tq < s; ++tq) {
    floatx16 p = mm3(sY[0], sY[1], sY[0], sY[1], R, ln, q, col);
    float w[16];
#pragma unroll
    for (int r = 0; r < 16; ++r) w[r] = p[r];
    __syncthreads();
    storeChl(sY[0], sY[1], w, R, col, q);
    __syncthreads();
  }
  // Gs -> sZ; W' = emu * E*Gs -> sW (direct layout; W' non-symmetric OK as
  // B-op); G1 = Gs*W' -> lA fp32.
  splitT(ws + GS_OFF, sZ[0], sZ[1], tid, 1.0f);
  __syncthreads();
  const float emu = expf(mu);
  {
    floatx16 p = mm3(sY[0], sY[1], sZ[0], sZ[1], R, ln, q, col);  // E*Gs
    float w[16];
#pragma unroll
    for (int r = 0; r < 16; ++r) w[r] = emu * p[r];
    storeChl(sW[0], sW[1], w, R, col, q);
  }
  __syncthreads();
  {
    floatx16 p = mm3(sZ[0], sZ[1], sW[0], sW[1], R, ln, q, col);  // Gs*W'
#pragma unroll
    for (int r = 0; r < 16; ++r) {
      int row = 32 * R + (r & 3) + 8 * (r >> 2) + 4 * q;
      lA[row * 64 + col] = p[r];
    }
  }
  __syncthreads();
  // symmetrize lA in place (register-buffered to avoid write/read race)
  {
    float sv[16], stt[16];
#pragma unroll
    for (int jb = 0; jb < 4; ++jb) {
      int flat = jb * 1024 + tid * 4;
      int i = flat >> 6, j0 = flat & 63;
      float4 v = *reinterpret_cast<const float4*>(lA + flat);
      sv[jb * 4 + 0] = v.x;
      sv[jb * 4 + 1] = v.y;
      sv[jb * 4 + 2] = v.z;
      sv[jb * 4 + 3] = v.w;
      stt[jb * 4 + 0] = lA[(j0 + 0) * 64 + i];
      stt[jb * 4 + 1] = lA[(j0 + 1) * 64 + i];
      stt[jb * 4 + 2] = lA[(j0 + 2) * 64 + i];
      stt[jb * 4 + 3] = lA[(j0 + 3) * 64 + i];
    }
    __syncthreads();
#pragma unroll
    for (int jb = 0; jb < 4; ++jb) {
      int flat = jb * 1024 + tid * 4;
      float4 v =
          make_float4(0.5f * (sv[jb * 4 + 0] + stt[jb * 4 + 0]),
                      0.5f * (sv[jb * 4 + 1] + stt[jb * 4 + 1]),
                      0.5f * (sv[jb * 4 + 2] + stt[jb * 4 + 2]),
                      0.5f * (sv[jb * 4 + 3] + stt[jb * 4 + 3]));
      *reinterpret_cast<float4*>(lA + flat) = v;
    }
  }
  __syncthreads();
  // Gis1 = G1^{-1/2}: NS on MFMA. Z holds Gis1 * sqrt(c).
  float c = block_ns_mfma(lA, sY[0], sY[1], sZ[0], sZ[1], sW[0], sW[1], red,
                          NS_ITERS_MEAN);
  const float rs = 1.0f / sqrtf(c);
  // Bs -> sA (free); C = rs * Bs*Z -> ws fp32.
  splitT(ws + BS_OFF, sA[0], sA[1], tid, 1.0f);
  __syncthreads();
  {
    floatx16 p = mm3(sA[0], sA[1], sZ[0], sZ[1], R, ln, q, col);
#pragma unroll
    for (int r = 0; r < 16; ++r) {
      int row = 32 * R + (r & 3) + 8 * (r >> 2) + 4 * q;
      ws[C_OFF + row * 64 + col] = p[r] * rs;
    }
  }
}

// ============================ K5: out = C X C^T (MFMA) ======================
// 1024 threads = 4 chains, grid 256 (1 block/CU, 16 waves). C^T staged once
// per block into a shared LDS pair. 2 LDS arrays per chain: X then P'
// time-share (A0,A1) with one extra barrier.
__global__ __attribute__((amdgpu_flat_work_group_size(1024, 1024),
                          amdgpu_waves_per_eu(4, 4))) void
k5_out_mfma(const float* __restrict__ x, const float* __restrict__ ws,
            float* __restrict__ out) {
  __shared__ __align__(16) short CtH[GSTR * 8], CtL[GSTR * 8];
  __shared__ __align__(16) short SH[K5_CHAINS][2][GSTR * 8];
  const int tid = threadIdx.x;
  const int ch = tid >> 8;
  const int ct = tid & 255;
  const int w4 = ct >> 6;
  const int R = w4 >> 1, Cb = w4 & 1;
  const int lane = tid & 63;
  const int ln = lane & 31, q = lane >> 5;
  const int col = 32 * Cb + ln;
  short* A0 = SH[ch][0];
  short* A1 = SH[ch][1];

  if (ch == 0) stageT(ws + C_OFF, CtH, CtL, ct);  // arr(k,n) = C[n][k]
  __syncthreads();

  for (int it = 0; it < CHAIN_MATS; ++it) {
    const int mat = blockIdx.x * (K5_CHAINS * CHAIN_MATS) + ch * CHAIN_MATS + it;
    stageT(x + (size_t)mat * MSIZE, A0, A1, ct);
    __syncthreads();
    floatx16 acc;
#pragma unroll
    for (int r = 0; r < 16; ++r) acc[r] = 0.0f;
#pragma unroll
    for (int kb = 0; kb < 4; ++kb) {
      bf16x8 axh = readFrag(A0, kb, q, 32 * R + ln);
      bf16x8 axl = readFrag(A1, kb, q, 32 * R + ln);
      bf16x8 cbh = readFrag(CtH, kb, q, col);  // B-op C^T
      bf16x8 cbl = readFrag(CtL, kb, q, col);
      acc = MFMA(axl, cbh, acc);
      acc = MFMA(axh, cbl, acc);
      acc = MFMA(axh, cbh, acc);
    }
    __syncthreads();  // all waves finished reading X
    float tmp[16];
#pragma unroll
    for (int r = 0; r < 16; ++r) tmp[r] = acc[r];
    storeChl(A0, A1, tmp, R, col, q);  // P' overwrites X
    __syncthreads();
#pragma unroll
    for (int r = 0; r < 16; ++r) acc[r] = 0.0f;
#pragma unroll
    for (int kb = 0; kb < 4; ++kb) {
      bf16x8 cah = readFrag(CtH, kb, q, 32 * R + ln);  // A-op C
      bf16x8 cal = readFrag(CtL, kb, q, 32 * R + ln);
      bf16x8 bph = readFrag(A0, kb, q, col);
      bf16x8 bpl = readFrag(A1, kb, q, col);
      acc = MFMA(cal, bph, acc);
      acc = MFMA(cah, bpl, acc);
      acc = MFMA(cah, bph, acc);
    }
    float* dst = out + (size_t)mat * MSIZE;
#pragma unroll
    for (int r = 0; r < 16; ++r) {
      int row = 32 * R + (r & 3) + 8 * (r >> 2) + 4 * q;
      dst[row * 64 + col] = acc[r];
    }
    __syncthreads();
  }
}

extern "C" void kernel_launch(void* const* d_in, const int* in_sizes, int n_in,
                              void* d_out, int out_size, void* d_ws,
                              size_t ws_size, hipStream_t stream) {
  const float* x = (const float*)d_in[0];
  const float* bias = (const float*)d_in[1];
  float* out = (float*)d_out;
  float* ws = (float*)d_ws;
  const float invB = 1.0f / (float)BATCH;
  float* red1 = out + (size_t)RED1_SLOT * MSIZE;  // 64 stage-1 slots in out

  k1_mean_bias<<<NBLK_RED + 1, 256, 0, stream>>>(x, bias, ws, out);
  k_reduce_parts<<<dim3(4, 32), 256, 0, stream>>>(out, red1, NBLK_RED, 1.0f);
  k_reduce_parts<<<dim3(4, 1), 256, 0, stream>>>(red1, ws + G_OFF, 32, invB);
  k2_mean_ns<<<1, 256, 0, stream>>>(ws);
  k3_logsum_mfma<<<NBLK_K3, 768, 0, stream>>>(x, ws, out);
  k_reduce_parts<<<dim3(4, 64), 256, 0, stream>>>(out, red1,
                                                  NBLK_K3 * K3_CHAINS, 1.0f);
  k_reduce_parts<<<dim3(4, 1), 256, 0, stream>>>(red1, ws + MBAR_OFF, 64, invB);
  k4_center<<<1, 256, 0, stream>>>(ws);
  k5_out_mfma<<<NBLK_K5, 1024, 0, stream>>>(x, ws, out);
}